// Round 4
// baseline (650.398 us; speedup 1.0000x reference)
//
#include <hip/hip_runtime.h>
#include <math.h>

#define NN 20000   // nodes
#define NE 480000  // edges
#define NB 4       // batch
#define ND 32      // dim
#define NR 474     // relations
#define NL 3       // layers
#define NT 64      // tails
#define M_TOT (NB * NN)   // 80000 node-rows

// ---------------- CSR build ----------------
__global__ __launch_bounds__(256) void count_kernel(const int* __restrict__ dst,
                                                    int* __restrict__ indeg) {
    int e = blockIdx.x * blockDim.x + threadIdx.x;
    if (e < NE) atomicAdd(&indeg[dst[e]], 1);
}

__global__ __launch_bounds__(1024) void scan_kernel(const int* __restrict__ indeg,
                                                    int* __restrict__ offsets) {
    __shared__ int sums[1024];
    int tid = threadIdx.x;
    const int chunk = (NN + 1023) / 1024;  // 20
    int start = tid * chunk;
    int end = start + chunk; if (end > NN) end = NN; if (start > NN) start = NN;
    int s = 0;
    for (int i = start; i < end; ++i) s += indeg[i];
    sums[tid] = s;
    __syncthreads();
    for (int off = 1; off < 1024; off <<= 1) {
        int v = (tid >= off) ? sums[tid - off] : 0;
        __syncthreads();
        sums[tid] += v;
        __syncthreads();
    }
    int base = (tid > 0) ? sums[tid - 1] : 0;
    for (int i = start; i < end; ++i) { offsets[i] = base; base += indeg[i]; }
    if (tid == 1023) offsets[NN] = sums[1023];
}

__global__ __launch_bounds__(256) void scatter_kernel(const int* __restrict__ src,
                                                      const int* __restrict__ dst,
                                                      const int* __restrict__ etype,
                                                      const int* __restrict__ offsets,
                                                      int* __restrict__ cursor,
                                                      int2* __restrict__ csr) {
    int e = blockIdx.x * blockDim.x + threadIdx.x;
    if (e < NE) {
        int dn = dst[e];
        int pos = atomicAdd(&cursor[dn], 1);
        csr[offsets[dn] + pos] = make_int2(src[e], etype[e]);
    }
}

// ---------------- degree-scale sum ----------------
__global__ __launch_bounds__(256) void logsum_kernel(const int* __restrict__ indeg,
                                                     float* __restrict__ ssum) {
    int n = blockIdx.x * blockDim.x + threadIdx.x;
    float v = (n < NN) ? logf((float)(indeg[n] + 2)) : 0.f;  // log(deg+1), deg = indeg+1
    #pragma unroll
    for (int off = 32; off > 0; off >>= 1) v += __shfl_down(v, off, 64);
    if ((threadIdx.x & 63) == 0) atomicAdd(ssum, v);
}

// ---------------- boundary init ----------------
__global__ void init_hidden_kernel(float* __restrict__ h0, const int* __restrict__ h_index,
                                   const int* __restrict__ r_index,
                                   const float* __restrict__ qw) {
    int i = threadIdx.x;  // 128 = NB*ND threads
    int b = i >> 5, d = i & 31;
    h0[(size_t)b * NN * ND + (size_t)h_index[b] * ND + d] = qw[r_index[b] * ND + d];
}

// ---------------- per-layer relation embeddings: rel[l][b][r][d] ----------------
__global__ __launch_bounds__(256) void rel_kernel(const float* __restrict__ qw,
                                                  const int* __restrict__ r_index,
                                                  const float* __restrict__ rlw,
                                                  float* __restrict__ rel) {
    int i = blockIdx.x * blockDim.x + threadIdx.x;
    if (i >= NL * NB * NR * ND) return;
    int d = i & (ND - 1);
    int r = (i / ND) % NR;
    int b = (i / (ND * NR)) % NB;
    int l = i / (ND * NR * NB);
    const float* q = qw + r_index[b] * ND;
    const float* w = rlw + (size_t)l * ND * NR * ND + (size_t)r * ND + d;
    float acc = 0.f;
    #pragma unroll
    for (int k = 0; k < ND; ++k) acc += q[k] * w[(size_t)k * NR * ND];
    rel[i] = acc;
}

// ---------------- aggregation + PNA stats -> transposed feature matrix ----------------
// 512 threads = 16 node-groups of 32 lanes. Only 11 KiB LDS -> ~full occupancy.
// Writes At[k][i] (k = 0..159: h(32), mean(32), max(32), min(32), std(32)),
// coalesced 64B rows via LDS transpose. Scalers are applied in gemm_kernel.
__global__ __launch_bounds__(512) void agg_kernel(
    const float* __restrict__ hin, float* __restrict__ At,
    const float* __restrict__ rel,               // [B][R][D] for this layer
    const int* __restrict__ offsets, const int2* __restrict__ csr,
    const int* __restrict__ h_index, const int* __restrict__ r_index,
    const float* __restrict__ qw) {
    __shared__ float tr[160][17];                // +1 pad: conflict-free col writes
    int tid = threadIdx.x;
    int g = tid >> 5, d = tid & 31;
    int idx = blockIdx.x * 16 + g;               // in [0, M_TOT)
    int b = idx / NN, n = idx - b * NN;
    const float* hb = hin + (size_t)b * NN * ND;
    const float* relb = rel + (size_t)b * NR * ND;

    float bm = (n == h_index[b]) ? qw[r_index[b] * ND + d] : 0.f;  // boundary self-msg
    float s = bm, ss = bm * bm, mx = bm, mn = bm;
    int beg = offsets[n], end = offsets[n + 1];
    int e = beg;
    for (; e + 4 <= end; e += 4) {
        int2 a0 = csr[e + 0];
        int2 a1 = csr[e + 1];
        int2 a2 = csr[e + 2];
        int2 a3 = csr[e + 3];
        float h0 = hb[(size_t)a0.x * ND + d], r0 = relb[(size_t)a0.y * ND + d];
        float h1 = hb[(size_t)a1.x * ND + d], r1 = relb[(size_t)a1.y * ND + d];
        float h2 = hb[(size_t)a2.x * ND + d], r2 = relb[(size_t)a2.y * ND + d];
        float h3 = hb[(size_t)a3.x * ND + d], r3 = relb[(size_t)a3.y * ND + d];
        float m0 = h0 * r0, m1 = h1 * r1, m2 = h2 * r2, m3 = h3 * r3;
        s += (m0 + m1) + (m2 + m3);
        ss += (m0 * m0 + m1 * m1) + (m2 * m2 + m3 * m3);
        mx = fmaxf(mx, fmaxf(fmaxf(m0, m1), fmaxf(m2, m3)));
        mn = fminf(mn, fminf(fminf(m0, m1), fminf(m2, m3)));
    }
    for (; e < end; ++e) {
        int2 se = csr[e];
        float m = hb[(size_t)se.x * ND + d] * relb[(size_t)se.y * ND + d];
        s += m; ss += m * m; mx = fmaxf(mx, m); mn = fminf(mn, m);
    }
    float degf = (float)(end - beg + 1);
    float inv = 1.0f / degf;
    float mean = s * inv;
    float stdv = sqrtf(fmaxf(ss * inv - mean * mean, 0.f));
    float h = hb[(size_t)n * ND + d];
    tr[d][g] = h;
    tr[32 + d][g] = mean;
    tr[64 + d][g] = mx;
    tr[96 + d][g] = mn;
    tr[128 + d][g] = stdv;
    __syncthreads();

    int r = tid >> 4, c = tid & 15;
    size_t col = (size_t)blockIdx.x * 16 + c;
    for (int rr = r; rr < 160; rr += 32)
        At[(size_t)rr * M_TOT + col] = tr[rr][c];
}

// ---------------- update GEMM: node-per-lane + 4-way K-split ----------------
// Block: 256 threads = 4 waves over TN=64 nodes. Wave kq (= tid>>6, uniform)
// accumulates interleaved rows kq, kq+4, ... so W loads stay SGPR (scalar).
// Partials reduced via LDS [4][64][33] (2-way banks = free). Epilogue:
// bias + relu + residual (coalesced read from hin), coalesced write.
__global__ __launch_bounds__(256, 4) void gemm_kernel(
    const float* __restrict__ At, const float* __restrict__ hin,
    float* __restrict__ hnew,
    const float* __restrict__ W, const float* __restrict__ bias,
    const int* __restrict__ offsets, const float* __restrict__ ssum) {
    __shared__ float part[4][64][33];
    int t = threadIdx.x;
    int node = t & 63, kq = t >> 6;              // kq wave-uniform
    int i = blockIdx.x * 64 + node;              // node-row, grid covers M_TOT
    float acc[32];
    #pragma unroll
    for (int j = 0; j < 32; ++j) acc[j] = 0.f;

    int n = i % NN;
    float degf = (float)(offsets[n + 1] - offsets[n] + 1);
    float scl = logf(degf + 1.0f) * ((float)NN / *ssum);
    float sc1 = scl, sc2 = 1.0f / fmaxf(scl, 1e-2f);

    // h block: rows kq, kq+4, ..., 28  (8 rows, 1 weight block each)
    #pragma unroll 4
    for (int kk = kq; kk < 32; kk += 4) {
        float a = At[(size_t)kk * M_TOT + i];
        #pragma unroll
        for (int j = 0; j < 32; ++j) acc[j] += a * W[kk * 32 + j];
    }
    // PNA blocks: rows 32+kq, ..., 156 (32 rows, 3 weight blocks each)
    #pragma unroll 4
    for (int kk = 32 + kq; kk < 160; kk += 4) {
        float a = At[(size_t)kk * M_TOT + i];
        float a1 = a * sc1, a2 = a * sc2;
        #pragma unroll
        for (int j = 0; j < 32; ++j)
            acc[j] += a * W[kk * 32 + j] + a1 * W[(kk + 128) * 32 + j] + a2 * W[(kk + 256) * 32 + j];
    }
    #pragma unroll
    for (int j = 0; j < 32; ++j) part[kq][node][j] = acc[j];
    __syncthreads();

    size_t obase = (size_t)blockIdx.x * 64 * 32;
    #pragma unroll
    for (int p = 0; p < 8; ++p) {
        int flat = p * 256 + t;                  // 0..2047
        int nd = flat >> 5, j = flat & 31;
        float v = part[0][nd][j] + part[1][nd][j] + part[2][nd][j] + part[3][nd][j];
        hnew[obase + flat] = fmaxf(v + bias[j], 0.f) + hin[obase + flat];
    }
}

// ---------------- final MLP scorer ----------------
__global__ __launch_bounds__(256) void score_kernel(
    const float* __restrict__ hidden, const int* __restrict__ t_index,
    const int* __restrict__ r_index, const float* __restrict__ qw,
    const float* __restrict__ w1, const float* __restrict__ b1,
    const float* __restrict__ w2, const float* __restrict__ b2,
    float* __restrict__ out) {
    int i = blockIdx.x * blockDim.x + threadIdx.x;
    if (i >= NB * NT) return;
    int b = i / NT;
    int node = t_index[i];
    float feat[2 * ND];
    #pragma unroll
    for (int d = 0; d < ND; ++d)
        feat[d] = hidden[(size_t)b * NN * ND + (size_t)node * ND + d];
    const float* q = qw + r_index[b] * ND;
    #pragma unroll
    for (int d = 0; d < ND; ++d) feat[ND + d] = q[d];
    float acc2 = b2[0];
    for (int j = 0; j < 2 * ND; ++j) {
        float a = b1[j];
        #pragma unroll
        for (int kk = 0; kk < 2 * ND; ++kk) a += feat[kk] * w1[kk * 2 * ND + j];
        acc2 += fmaxf(a, 0.f) * w2[j];
    }
    out[i] = acc2;
}

extern "C" void kernel_launch(void* const* d_in, const int* in_sizes, int n_in,
                              void* d_out, int out_size, void* d_ws, size_t ws_size,
                              hipStream_t stream) {
    (void)in_sizes; (void)n_in; (void)out_size; (void)ws_size;
    const int* edge_index = (const int*)d_in[0];     // [2][E]
    const int* edge_type  = (const int*)d_in[1];     // [E]
    const int* h_index    = (const int*)d_in[2];     // [B]
    const int* r_index    = (const int*)d_in[3];     // [B]
    const int* t_index    = (const int*)d_in[4];     // [B][T]
    const float* query_weight = (const float*)d_in[5];  // [R][D]
    const float* rel_lin_w    = (const float*)d_in[6];  // [L][D][R*D]
    const float* layer_w      = (const float*)d_in[7];  // [L][13D][D]
    const float* layer_b      = (const float*)d_in[8];  // [L][D]
    const float* mlp_w1 = (const float*)d_in[9];
    const float* mlp_b1 = (const float*)d_in[10];
    const float* mlp_w2 = (const float*)d_in[11];
    const float* mlp_b2 = (const float*)d_in[12];
    float* out = (float*)d_out;

    const int* src = edge_index;
    const int* dst = edge_index + NE;

    char* wsp = (char*)d_ws;
    size_t off = 0;
    auto alloc = [&](size_t bytes) -> void* {
        void* p = wsp + off;
        off += (bytes + 255) & ~(size_t)255;
        return p;
    };
    float* h0      = (float*)alloc(sizeof(float) * M_TOT * ND);
    float* h1      = (float*)alloc(sizeof(float) * M_TOT * ND);
    float* At      = (float*)alloc(sizeof(float) * 160 * M_TOT);   // 51.2 MB
    float* rel     = (float*)alloc(sizeof(float) * NL * NB * NR * ND);
    int2*  csr     = (int2*)alloc(sizeof(int2) * NE);
    int*   offsets = (int*)alloc(sizeof(int) * (NN + 1));
    int*   cursor  = (int*)alloc(sizeof(int) * NN);
    int*   indeg   = (int*)alloc(sizeof(int) * NN);
    float* ssum    = (float*)alloc(256);

    hipMemsetAsync(indeg, 0, sizeof(int) * NN, stream);
    hipMemsetAsync(cursor, 0, sizeof(int) * NN, stream);
    hipMemsetAsync(ssum, 0, sizeof(float), stream);
    hipMemsetAsync(h0, 0, sizeof(float) * M_TOT * ND, stream);

    count_kernel<<<(NE + 255) / 256, 256, 0, stream>>>(dst, indeg);
    scan_kernel<<<1, 1024, 0, stream>>>(indeg, offsets);
    scatter_kernel<<<(NE + 255) / 256, 256, 0, stream>>>(src, dst, edge_type, offsets, cursor, csr);
    logsum_kernel<<<(NN + 255) / 256, 256, 0, stream>>>(indeg, ssum);
    init_hidden_kernel<<<1, NB * ND, 0, stream>>>(h0, h_index, r_index, query_weight);

    int rel_total = NL * NB * NR * ND;
    rel_kernel<<<(rel_total + 255) / 256, 256, 0, stream>>>(query_weight, r_index, rel_lin_w, rel);

    float* hin = h0;
    float* hout = h1;
    for (int l = 0; l < NL; ++l) {
        agg_kernel<<<M_TOT / 16, 512, 0, stream>>>(
            hin, At, rel + (size_t)l * NB * NR * ND,
            offsets, csr, h_index, r_index, query_weight);
        gemm_kernel<<<M_TOT / 64, 256, 0, stream>>>(
            At, hin, hout, layer_w + (size_t)l * 13 * ND * ND, layer_b + (size_t)l * ND,
            offsets, ssum);
        float* t = hin; hin = hout; hout = t;
    }
    // final hidden is in `hin`

    score_kernel<<<1, 256, 0, stream>>>(hin, t_index, r_index, query_weight,
                                        mlp_w1, mlp_b1, mlp_w2, mlp_b2, out);
}

// Round 5
// 511.867 us; speedup vs baseline: 1.2706x; 1.2706x over previous
//
#include <hip/hip_runtime.h>
#include <math.h>

#define NN 20000   // nodes
#define NE 480000  // edges
#define NB 4       // batch
#define ND 32      // dim
#define NR 474     // relations
#define NL 3       // layers
#define NT 64      // tails
#define M_TOT (NB * NN)   // 80000 node-rows

// ---------------- CSR build ----------------
__global__ __launch_bounds__(256) void count_kernel(const int* __restrict__ dst,
                                                    int* __restrict__ indeg) {
    int e = blockIdx.x * blockDim.x + threadIdx.x;
    if (e < NE) atomicAdd(&indeg[dst[e]], 1);
}

__global__ __launch_bounds__(1024) void scan_kernel(const int* __restrict__ indeg,
                                                    int* __restrict__ offsets) {
    __shared__ int sums[1024];
    int tid = threadIdx.x;
    const int chunk = (NN + 1023) / 1024;  // 20
    int start = tid * chunk;
    int end = start + chunk; if (end > NN) end = NN; if (start > NN) start = NN;
    int s = 0;
    for (int i = start; i < end; ++i) s += indeg[i];
    sums[tid] = s;
    __syncthreads();
    for (int off = 1; off < 1024; off <<= 1) {
        int v = (tid >= off) ? sums[tid - off] : 0;
        __syncthreads();
        sums[tid] += v;
        __syncthreads();
    }
    int base = (tid > 0) ? sums[tid - 1] : 0;
    for (int i = start; i < end; ++i) { offsets[i] = base; base += indeg[i]; }
    if (tid == 1023) offsets[NN] = sums[1023];
}

__global__ __launch_bounds__(256) void scatter_kernel(const int* __restrict__ src,
                                                      const int* __restrict__ dst,
                                                      const int* __restrict__ etype,
                                                      const int* __restrict__ offsets,
                                                      int* __restrict__ cursor,
                                                      int2* __restrict__ csr) {
    int e = blockIdx.x * blockDim.x + threadIdx.x;
    if (e < NE) {
        int dn = dst[e];
        int pos = atomicAdd(&cursor[dn], 1);
        csr[offsets[dn] + pos] = make_int2(src[e], etype[e]);
    }
}

// ---------------- degree-scale sum ----------------
__global__ __launch_bounds__(256) void logsum_kernel(const int* __restrict__ indeg,
                                                     float* __restrict__ ssum) {
    int n = blockIdx.x * blockDim.x + threadIdx.x;
    float v = (n < NN) ? logf((float)(indeg[n] + 2)) : 0.f;  // log(deg+1), deg = indeg+1
    #pragma unroll
    for (int off = 32; off > 0; off >>= 1) v += __shfl_down(v, off, 64);
    if ((threadIdx.x & 63) == 0) atomicAdd(ssum, v);
}

// ---------------- boundary init ----------------
__global__ void init_hidden_kernel(float* __restrict__ h0, const int* __restrict__ h_index,
                                   const int* __restrict__ r_index,
                                   const float* __restrict__ qw) {
    int i = threadIdx.x;  // 128 = NB*ND threads
    int b = i >> 5, d = i & 31;
    h0[(size_t)b * NN * ND + (size_t)h_index[b] * ND + d] = qw[r_index[b] * ND + d];
}

// ---------------- per-layer relation embeddings: rel[l][b][r][d] ----------------
__global__ __launch_bounds__(256) void rel_kernel(const float* __restrict__ qw,
                                                  const int* __restrict__ r_index,
                                                  const float* __restrict__ rlw,
                                                  float* __restrict__ rel) {
    int i = blockIdx.x * blockDim.x + threadIdx.x;
    if (i >= NL * NB * NR * ND) return;
    int d = i & (ND - 1);
    int r = (i / ND) % NR;
    int b = (i / (ND * NR)) % NB;
    int l = i / (ND * NR * NB);
    const float* q = qw + r_index[b] * ND;
    const float* w = rlw + (size_t)l * ND * NR * ND + (size_t)r * ND + d;
    float acc = 0.f;
    #pragma unroll
    for (int k = 0; k < ND; ++k) acc += q[k] * w[(size_t)k * NR * ND];
    rel[i] = acc;
}

// ---------------- aggregation + PNA stats -> transposed feature matrix ----------------
// 512 threads = 16 node-groups of 32 lanes. Only 11 KiB LDS -> ~full occupancy.
// Writes At[k][i] (k = 0..159: h(32), mean(32), max(32), min(32), std(32)),
// coalesced 64B rows via LDS transpose. Scalers are applied in gemm_kernel.
__global__ __launch_bounds__(512) void agg_kernel(
    const float* __restrict__ hin, float* __restrict__ At,
    const float* __restrict__ rel,               // [B][R][D] for this layer
    const int* __restrict__ offsets, const int2* __restrict__ csr,
    const int* __restrict__ h_index, const int* __restrict__ r_index,
    const float* __restrict__ qw) {
    __shared__ float tr[160][17];                // +1 pad: conflict-free col writes
    int tid = threadIdx.x;
    int g = tid >> 5, d = tid & 31;
    int idx = blockIdx.x * 16 + g;               // in [0, M_TOT)
    int b = idx / NN, n = idx - b * NN;
    const float* hb = hin + (size_t)b * NN * ND;
    const float* relb = rel + (size_t)b * NR * ND;

    float bm = (n == h_index[b]) ? qw[r_index[b] * ND + d] : 0.f;  // boundary self-msg
    float s = bm, ss = bm * bm, mx = bm, mn = bm;
    int beg = offsets[n], end = offsets[n + 1];
    int e = beg;
    for (; e + 4 <= end; e += 4) {
        int2 a0 = csr[e + 0];
        int2 a1 = csr[e + 1];
        int2 a2 = csr[e + 2];
        int2 a3 = csr[e + 3];
        float h0 = hb[(size_t)a0.x * ND + d], r0 = relb[(size_t)a0.y * ND + d];
        float h1 = hb[(size_t)a1.x * ND + d], r1 = relb[(size_t)a1.y * ND + d];
        float h2 = hb[(size_t)a2.x * ND + d], r2 = relb[(size_t)a2.y * ND + d];
        float h3 = hb[(size_t)a3.x * ND + d], r3 = relb[(size_t)a3.y * ND + d];
        float m0 = h0 * r0, m1 = h1 * r1, m2 = h2 * r2, m3 = h3 * r3;
        s += (m0 + m1) + (m2 + m3);
        ss += (m0 * m0 + m1 * m1) + (m2 * m2 + m3 * m3);
        mx = fmaxf(mx, fmaxf(fmaxf(m0, m1), fmaxf(m2, m3)));
        mn = fminf(mn, fminf(fminf(m0, m1), fminf(m2, m3)));
    }
    for (; e < end; ++e) {
        int2 se = csr[e];
        float m = hb[(size_t)se.x * ND + d] * relb[(size_t)se.y * ND + d];
        s += m; ss += m * m; mx = fmaxf(mx, m); mn = fminf(mn, m);
    }
    float degf = (float)(end - beg + 1);
    float inv = 1.0f / degf;
    float mean = s * inv;
    float stdv = sqrtf(fmaxf(ss * inv - mean * mean, 0.f));
    float h = hb[(size_t)n * ND + d];
    tr[d][g] = h;
    tr[32 + d][g] = mean;
    tr[64 + d][g] = mx;
    tr[96 + d][g] = mn;
    tr[128 + d][g] = stdv;
    __syncthreads();

    int r = tid >> 4, c = tid & 15;
    size_t col = (size_t)blockIdx.x * 16 + c;
    for (int rr = r; rr < 160; rr += 32)
        At[(size_t)rr * M_TOT + col] = tr[rr][c];
}

// ---------------- update GEMM: node-per-lane, W broadcast from LDS ----------------
// Each thread owns one node-row: acc[32] in VGPRs; per k-row one coalesced
// VMEM load of a = At[k][i], then W[k][*] read as wave-uniform ds_read_b128
// broadcasts (conflict-free). No SGPR W -> no scalar-cache thrash.
// LDS 53 KiB -> 2 blocks/CU = 16 waves/CU.
__global__ __launch_bounds__(512) void gemm_kernel(
    const float* __restrict__ At, const float* __restrict__ hin,
    float* __restrict__ hnew,
    const float* __restrict__ W, const float* __restrict__ bias,
    const int* __restrict__ offsets, const float* __restrict__ ssum) {
    __shared__ float ldsW[13 * ND * ND];   // 13312 floats = 52 KiB
    __shared__ float ldsB[ND];
    int t = threadIdx.x;
    for (int p = t; p < 13 * ND * ND; p += 512) ldsW[p] = W[p];
    if (t < ND) ldsB[t] = bias[t];
    __syncthreads();

    int i = blockIdx.x * 512 + t;
    if (i >= M_TOT) return;

    float acc[32];
    #pragma unroll
    for (int j = 0; j < 32; ++j) acc[j] = 0.f;

    int n = i % NN;
    float degf = (float)(offsets[n + 1] - offsets[n] + 1);
    float scl = logf(degf + 1.0f) * ((float)NN / *ssum);
    float sc1 = scl, sc2 = 1.0f / fmaxf(scl, 1e-2f);

    const float4* W4 = (const float4*)ldsW;

    // h block: rows 0..31, one weight block each
    #pragma unroll 2
    for (int kk = 0; kk < 32; ++kk) {
        float a = At[(size_t)kk * M_TOT + i];
        #pragma unroll
        for (int q = 0; q < 8; ++q) {
            float4 w = W4[kk * 8 + q];
            acc[4 * q + 0] += a * w.x;
            acc[4 * q + 1] += a * w.y;
            acc[4 * q + 2] += a * w.z;
            acc[4 * q + 3] += a * w.w;
        }
    }
    // PNA blocks: rows 32..159, three weight blocks each (identity, sc1, sc2)
    #pragma unroll 2
    for (int kk = 32; kk < 160; ++kk) {
        float a = At[(size_t)kk * M_TOT + i];
        float a1 = a * sc1, a2 = a * sc2;
        #pragma unroll
        for (int q = 0; q < 8; ++q) {
            float4 w = W4[kk * 8 + q];
            float4 u = W4[(kk + 128) * 8 + q];
            float4 v = W4[(kk + 256) * 8 + q];
            acc[4 * q + 0] += a * w.x + a1 * u.x + a2 * v.x;
            acc[4 * q + 1] += a * w.y + a1 * u.y + a2 * v.y;
            acc[4 * q + 2] += a * w.z + a1 * u.z + a2 * v.z;
            acc[4 * q + 3] += a * w.w + a1 * u.w + a2 * v.w;
        }
    }

    // epilogue: bias + relu + residual, float4 loads/stores
    size_t base = (size_t)i * 32;
    const float4* hin4 = (const float4*)(hin + base);
    float4* out4 = (float4*)(hnew + base);
    #pragma unroll
    for (int q = 0; q < 8; ++q) {
        float4 h4 = hin4[q];
        float4 o;
        o.x = fmaxf(acc[4 * q + 0] + ldsB[4 * q + 0], 0.f) + h4.x;
        o.y = fmaxf(acc[4 * q + 1] + ldsB[4 * q + 1], 0.f) + h4.y;
        o.z = fmaxf(acc[4 * q + 2] + ldsB[4 * q + 2], 0.f) + h4.z;
        o.w = fmaxf(acc[4 * q + 3] + ldsB[4 * q + 3], 0.f) + h4.w;
        out4[q] = o;
    }
}

// ---------------- final MLP scorer ----------------
__global__ __launch_bounds__(256) void score_kernel(
    const float* __restrict__ hidden, const int* __restrict__ t_index,
    const int* __restrict__ r_index, const float* __restrict__ qw,
    const float* __restrict__ w1, const float* __restrict__ b1,
    const float* __restrict__ w2, const float* __restrict__ b2,
    float* __restrict__ out) {
    int i = blockIdx.x * blockDim.x + threadIdx.x;
    if (i >= NB * NT) return;
    int b = i / NT;
    int node = t_index[i];
    float feat[2 * ND];
    #pragma unroll
    for (int d = 0; d < ND; ++d)
        feat[d] = hidden[(size_t)b * NN * ND + (size_t)node * ND + d];
    const float* q = qw + r_index[b] * ND;
    #pragma unroll
    for (int d = 0; d < ND; ++d) feat[ND + d] = q[d];
    float acc2 = b2[0];
    for (int j = 0; j < 2 * ND; ++j) {
        float a = b1[j];
        #pragma unroll
        for (int kk = 0; kk < 2 * ND; ++kk) a += feat[kk] * w1[kk * 2 * ND + j];
        acc2 += fmaxf(a, 0.f) * w2[j];
    }
    out[i] = acc2;
}

extern "C" void kernel_launch(void* const* d_in, const int* in_sizes, int n_in,
                              void* d_out, int out_size, void* d_ws, size_t ws_size,
                              hipStream_t stream) {
    (void)in_sizes; (void)n_in; (void)out_size; (void)ws_size;
    const int* edge_index = (const int*)d_in[0];     // [2][E]
    const int* edge_type  = (const int*)d_in[1];     // [E]
    const int* h_index    = (const int*)d_in[2];     // [B]
    const int* r_index    = (const int*)d_in[3];     // [B]
    const int* t_index    = (const int*)d_in[4];     // [B][T]
    const float* query_weight = (const float*)d_in[5];  // [R][D]
    const float* rel_lin_w    = (const float*)d_in[6];  // [L][D][R*D]
    const float* layer_w      = (const float*)d_in[7];  // [L][13D][D]
    const float* layer_b      = (const float*)d_in[8];  // [L][D]
    const float* mlp_w1 = (const float*)d_in[9];
    const float* mlp_b1 = (const float*)d_in[10];
    const float* mlp_w2 = (const float*)d_in[11];
    const float* mlp_b2 = (const float*)d_in[12];
    float* out = (float*)d_out;

    const int* src = edge_index;
    const int* dst = edge_index + NE;

    char* wsp = (char*)d_ws;
    size_t off = 0;
    auto alloc = [&](size_t bytes) -> void* {
        void* p = wsp + off;
        off += (bytes + 255) & ~(size_t)255;
        return p;
    };
    float* h0      = (float*)alloc(sizeof(float) * M_TOT * ND);
    float* h1      = (float*)alloc(sizeof(float) * M_TOT * ND);
    float* At      = (float*)alloc(sizeof(float) * 160 * M_TOT);   // 51.2 MB
    float* rel     = (float*)alloc(sizeof(float) * NL * NB * NR * ND);
    int2*  csr     = (int2*)alloc(sizeof(int2) * NE);
    int*   offsets = (int*)alloc(sizeof(int) * (NN + 1));
    int*   cursor  = (int*)alloc(sizeof(int) * NN);
    int*   indeg   = (int*)alloc(sizeof(int) * NN);
    float* ssum    = (float*)alloc(256);

    hipMemsetAsync(indeg, 0, sizeof(int) * NN, stream);
    hipMemsetAsync(cursor, 0, sizeof(int) * NN, stream);
    hipMemsetAsync(ssum, 0, sizeof(float), stream);
    hipMemsetAsync(h0, 0, sizeof(float) * M_TOT * ND, stream);

    count_kernel<<<(NE + 255) / 256, 256, 0, stream>>>(dst, indeg);
    scan_kernel<<<1, 1024, 0, stream>>>(indeg, offsets);
    scatter_kernel<<<(NE + 255) / 256, 256, 0, stream>>>(src, dst, edge_type, offsets, cursor, csr);
    logsum_kernel<<<(NN + 255) / 256, 256, 0, stream>>>(indeg, ssum);
    init_hidden_kernel<<<1, NB * ND, 0, stream>>>(h0, h_index, r_index, query_weight);

    int rel_total = NL * NB * NR * ND;
    rel_kernel<<<(rel_total + 255) / 256, 256, 0, stream>>>(query_weight, r_index, rel_lin_w, rel);

    float* hin = h0;
    float* hout = h1;
    for (int l = 0; l < NL; ++l) {
        agg_kernel<<<M_TOT / 16, 512, 0, stream>>>(
            hin, At, rel + (size_t)l * NB * NR * ND,
            offsets, csr, h_index, r_index, query_weight);
        gemm_kernel<<<(M_TOT + 511) / 512, 512, 0, stream>>>(
            At, hin, hout, layer_w + (size_t)l * 13 * ND * ND, layer_b + (size_t)l * ND,
            offsets, ssum);
        float* t = hin; hin = hout; hout = t;
    }
    // final hidden is in `hin`

    score_kernel<<<1, 256, 0, stream>>>(hin, t_index, r_index, query_weight,
                                        mlp_w1, mlp_b1, mlp_w2, mlp_b2, out);
}

// Round 6
// 317.950 us; speedup vs baseline: 2.0456x; 1.6099x over previous
//
#include <hip/hip_runtime.h>
#include <math.h>

#define NN 20000   // nodes
#define NE 480000  // edges
#define NB 4       // batch
#define ND 32      // dim
#define NR 474     // relations
#define NL 3       // layers
#define NT 64      // tails
#define M_TOT (NB * NN)   // 80000 node-rows
#define KA 160            // A columns: h(32) mean(32) mx(32) mn(32) std(32)

typedef __attribute__((ext_vector_type(8))) short bf16x8v;
typedef __attribute__((ext_vector_type(4))) float f32x4v;

// RNE split of f32 into bf16 hi + bf16 lo (a ~= hi + lo, err ~2^-18 rel)
__device__ inline void bf16split(float a, unsigned short& h, unsigned short& l) {
    unsigned u = __float_as_uint(a);
    unsigned r = u + 0x7FFFu + ((u >> 16) & 1u);
    h = (unsigned short)(r >> 16);
    float fh = __uint_as_float((unsigned)h << 16);
    float res = a - fh;
    unsigned v = __float_as_uint(res);
    unsigned r2 = v + 0x7FFFu + ((v >> 16) & 1u);
    l = (unsigned short)(r2 >> 16);
}

// ---------------- CSR build ----------------
__global__ __launch_bounds__(256) void count_kernel(const int* __restrict__ dst,
                                                    int* __restrict__ indeg) {
    int e = blockIdx.x * blockDim.x + threadIdx.x;
    if (e < NE) atomicAdd(&indeg[dst[e]], 1);
}

__global__ __launch_bounds__(1024) void scan_kernel(const int* __restrict__ indeg,
                                                    int* __restrict__ offsets) {
    __shared__ int sums[1024];
    int tid = threadIdx.x;
    const int chunk = (NN + 1023) / 1024;  // 20
    int start = tid * chunk;
    int end = start + chunk; if (end > NN) end = NN; if (start > NN) start = NN;
    int s = 0;
    for (int i = start; i < end; ++i) s += indeg[i];
    sums[tid] = s;
    __syncthreads();
    for (int off = 1; off < 1024; off <<= 1) {
        int v = (tid >= off) ? sums[tid - off] : 0;
        __syncthreads();
        sums[tid] += v;
        __syncthreads();
    }
    int base = (tid > 0) ? sums[tid - 1] : 0;
    for (int i = start; i < end; ++i) { offsets[i] = base; base += indeg[i]; }
    if (tid == 1023) offsets[NN] = sums[1023];
}

__global__ __launch_bounds__(256) void scatter_kernel(const int* __restrict__ src,
                                                      const int* __restrict__ dst,
                                                      const int* __restrict__ etype,
                                                      const int* __restrict__ offsets,
                                                      int* __restrict__ cursor,
                                                      int2* __restrict__ csr) {
    int e = blockIdx.x * blockDim.x + threadIdx.x;
    if (e < NE) {
        int dn = dst[e];
        int pos = atomicAdd(&cursor[dn], 1);
        csr[offsets[dn] + pos] = make_int2(src[e], etype[e]);
    }
}

// ---------------- degree-scale sum ----------------
__global__ __launch_bounds__(256) void logsum_kernel(const int* __restrict__ indeg,
                                                     float* __restrict__ ssum) {
    int n = blockIdx.x * blockDim.x + threadIdx.x;
    float v = (n < NN) ? logf((float)(indeg[n] + 2)) : 0.f;  // log(deg+1), deg = indeg+1
    #pragma unroll
    for (int off = 32; off > 0; off >>= 1) v += __shfl_down(v, off, 64);
    if ((threadIdx.x & 63) == 0) atomicAdd(ssum, v);
}

// sc1/sc2 per node, precomputed once
__global__ __launch_bounds__(256) void scales_kernel(const int* __restrict__ indeg,
                                                     const float* __restrict__ ssum,
                                                     float2* __restrict__ scales2) {
    int n = blockIdx.x * blockDim.x + threadIdx.x;
    if (n >= NN) return;
    float scl = logf((float)(indeg[n] + 2)) * ((float)NN / *ssum);
    scales2[n] = make_float2(scl, 1.0f / fmaxf(scl, 1e-2f));
}

// ---------------- boundary init ----------------
__global__ void init_hidden_kernel(float* __restrict__ h0, const int* __restrict__ h_index,
                                   const int* __restrict__ r_index,
                                   const float* __restrict__ qw) {
    int i = threadIdx.x;  // 128 = NB*ND threads
    int b = i >> 5, d = i & 31;
    h0[(size_t)b * NN * ND + (size_t)h_index[b] * ND + d] = qw[r_index[b] * ND + d];
}

// ---------------- per-layer relation embeddings: rel[l][b][r][d] ----------------
__global__ __launch_bounds__(256) void rel_kernel(const float* __restrict__ qw,
                                                  const int* __restrict__ r_index,
                                                  const float* __restrict__ rlw,
                                                  float* __restrict__ rel) {
    int i = blockIdx.x * blockDim.x + threadIdx.x;
    if (i >= NL * NB * NR * ND) return;
    int d = i & (ND - 1);
    int r = (i / ND) % NR;
    int b = (i / (ND * NR)) % NB;
    int l = i / (ND * NR * NB);
    const float* q = qw + r_index[b] * ND;
    const float* w = rlw + (size_t)l * ND * NR * ND + (size_t)r * ND + d;
    float acc = 0.f;
    #pragma unroll
    for (int k = 0; k < ND; ++k) acc += q[k] * w[(size_t)k * NR * ND];
    rel[i] = acc;
}

// ---------------- pack layer_w into MFMA B-fragment layout, bf16 hi/lo ----------------
// Wp[l][nt][s][lane][e]: value = W[l][k][n], k = s*32 + (lane>>4)*8 + e, n = nt*16 + (lane&15)
__global__ __launch_bounds__(256) void wpack_kernel(const float* __restrict__ W,
                                                    unsigned short* __restrict__ Wph,
                                                    unsigned short* __restrict__ Wpl) {
    int t = blockIdx.x * 256 + threadIdx.x;
    if (t >= NL * 2 * 13 * 64) return;
    int lane = t & 63;
    int u = t >> 6;
    int s = u % 13;
    int nt = (u / 13) % 2;
    int l = u / 26;
    int n = nt * 16 + (lane & 15);
    int k0 = s * 32 + (lane >> 4) * 8;
    size_t ob = (size_t)t * 8;
    #pragma unroll
    for (int e = 0; e < 8; ++e) {
        float w = W[(size_t)l * 416 * 32 + (size_t)(k0 + e) * 32 + n];
        unsigned short h8, l8;
        bf16split(w, h8, l8);
        Wph[ob + e] = h8;
        Wpl[ob + e] = l8;
    }
}

// ---------------- aggregation + PNA stats -> row-major bf16-split A[M][160] ----------------
// 512 threads = 16 node-groups of 32 lanes. No LDS -> high occupancy.
// A cols: h(0:32) mean(32:64) mx(64:96) mn(96:128) std(128:160). Scalers applied in GEMM epilogue.
__global__ __launch_bounds__(512) void agg_kernel(
    const float* __restrict__ hin,
    unsigned short* __restrict__ Ah, unsigned short* __restrict__ Al,
    const float* __restrict__ rel,               // [B][R][D] for this layer
    const int* __restrict__ offsets, const int2* __restrict__ csr,
    const int* __restrict__ h_index, const int* __restrict__ r_index,
    const float* __restrict__ qw) {
    int tid = threadIdx.x;
    int g = tid >> 5, d = tid & 31;
    int idx = blockIdx.x * 16 + g;               // in [0, M_TOT)
    int b = idx / NN, n = idx - b * NN;
    const float* hb = hin + (size_t)b * NN * ND;
    const float* relb = rel + (size_t)b * NR * ND;

    float bm = (n == h_index[b]) ? qw[r_index[b] * ND + d] : 0.f;  // boundary self-msg
    float s = bm, ss = bm * bm, mx = bm, mn = bm;
    int beg = offsets[n], end = offsets[n + 1];
    int e = beg;
    for (; e + 4 <= end; e += 4) {
        int2 a0 = csr[e + 0];
        int2 a1 = csr[e + 1];
        int2 a2 = csr[e + 2];
        int2 a3 = csr[e + 3];
        float h0 = hb[(size_t)a0.x * ND + d], r0 = relb[(size_t)a0.y * ND + d];
        float h1 = hb[(size_t)a1.x * ND + d], r1 = relb[(size_t)a1.y * ND + d];
        float h2 = hb[(size_t)a2.x * ND + d], r2 = relb[(size_t)a2.y * ND + d];
        float h3 = hb[(size_t)a3.x * ND + d], r3 = relb[(size_t)a3.y * ND + d];
        float m0 = h0 * r0, m1 = h1 * r1, m2 = h2 * r2, m3 = h3 * r3;
        s += (m0 + m1) + (m2 + m3);
        ss += (m0 * m0 + m1 * m1) + (m2 * m2 + m3 * m3);
        mx = fmaxf(mx, fmaxf(fmaxf(m0, m1), fmaxf(m2, m3)));
        mn = fminf(mn, fminf(fminf(m0, m1), fminf(m2, m3)));
    }
    for (; e < end; ++e) {
        int2 se = csr[e];
        float m = hb[(size_t)se.x * ND + d] * relb[(size_t)se.y * ND + d];
        s += m; ss += m * m; mx = fmaxf(mx, m); mn = fminf(mn, m);
    }
    float degf = (float)(end - beg + 1);
    float inv = 1.0f / degf;
    float mean = s * inv;
    float stdv = sqrtf(fmaxf(ss * inv - mean * mean, 0.f));
    float h = hb[(size_t)n * ND + d];

    size_t rb = (size_t)idx * KA;
    unsigned short vh, vl;
    bf16split(h,    vh, vl); Ah[rb +       d] = vh; Al[rb +       d] = vl;
    bf16split(mean, vh, vl); Ah[rb +  32 + d] = vh; Al[rb +  32 + d] = vl;
    bf16split(mx,   vh, vl); Ah[rb +  64 + d] = vh; Al[rb +  64 + d] = vl;
    bf16split(mn,   vh, vl); Ah[rb +  96 + d] = vh; Al[rb +  96 + d] = vl;
    bf16split(stdv, vh, vl); Ah[rb + 128 + d] = vh; Al[rb + 128 + d] = vl;
}

// ---------------- update GEMM via MFMA (split-bf16, f32-accurate) ----------------
// Wave = one 16x16 C tile: mtile = wv>>1 (rows), nt = wv&1 (cols 0:16 / 16:32).
// 3 accumulators: acc_a (h + unscaled PNA), acc2 (x sc1), acc3 (x sc2); scalers
// applied per-row in the epilogue (diag(sc) A W == diag(sc) (A W)).
__global__ __launch_bounds__(256) void gemm_mfma_kernel(
    const unsigned short* __restrict__ Ah, const unsigned short* __restrict__ Al,
    const unsigned short* __restrict__ Wph, const unsigned short* __restrict__ Wpl,
    const float* __restrict__ hin, float* __restrict__ hnew,
    const float* __restrict__ bias, const float2* __restrict__ scales2) {
    int tid = threadIdx.x;
    int wv = blockIdx.x * 4 + (tid >> 6);        // 10000 waves total
    int lane = tid & 63;
    int mtile = wv >> 1, nt = wv & 1;
    int am = lane & 15, kg = lane >> 4;

    size_t abase = ((size_t)(mtile * 16 + am)) * KA + kg * 8;
    bf16x8v ah[5], al[5];
    #pragma unroll
    for (int c = 0; c < 5; ++c) {
        ah[c] = *(const bf16x8v*)(Ah + abase + 32 * c);
        al[c] = *(const bf16x8v*)(Al + abase + 32 * c);
    }
    const bf16x8v* Bh = (const bf16x8v*)(Wph + (size_t)nt * 13 * 64 * 8);
    const bf16x8v* Bl = (const bf16x8v*)(Wpl + (size_t)nt * 13 * 64 * 8);

    f32x4v acc_a = {0.f, 0.f, 0.f, 0.f};
    f32x4v acc2  = {0.f, 0.f, 0.f, 0.f};
    f32x4v acc3  = {0.f, 0.f, 0.f, 0.f};

#define GSTEP(S, C, ACC)                                                          \
    {                                                                             \
        bf16x8v bh = Bh[(S) * 64 + lane];                                         \
        bf16x8v bl = Bl[(S) * 64 + lane];                                         \
        ACC = __builtin_amdgcn_mfma_f32_16x16x32_bf16(ah[C], bh, ACC, 0, 0, 0);   \
        ACC = __builtin_amdgcn_mfma_f32_16x16x32_bf16(ah[C], bl, ACC, 0, 0, 0);   \
        ACC = __builtin_amdgcn_mfma_f32_16x16x32_bf16(al[C], bh, ACC, 0, 0, 0);   \
    }
    GSTEP(0, 0, acc_a)
    GSTEP(1, 1, acc_a) GSTEP(2, 2, acc_a) GSTEP(3, 3, acc_a) GSTEP(4, 4, acc_a)
    GSTEP(5, 1, acc2)  GSTEP(6, 2, acc2)  GSTEP(7, 3, acc2)  GSTEP(8, 4, acc2)
    GSTEP(9, 1, acc3)  GSTEP(10, 2, acc3) GSTEP(11, 3, acc3) GSTEP(12, 4, acc3)
#undef GSTEP

    // Epilogue: C layout col = lane&15, row = 4*(lane>>4)+r (verified m89)
    int j = nt * 16 + am;
    float bj = bias[j];
    #pragma unroll
    for (int r = 0; r < 4; ++r) {
        int i = mtile * 16 + 4 * kg + r;
        int n = i % NN;
        float2 sc = scales2[n];
        float v = acc_a[r] + sc.x * acc2[r] + sc.y * acc3[r] + bj;
        size_t o = (size_t)i * 32 + j;
        hnew[o] = fmaxf(v, 0.f) + hin[o];
    }
}

// ---------------- final MLP scorer ----------------
__global__ __launch_bounds__(256) void score_kernel(
    const float* __restrict__ hidden, const int* __restrict__ t_index,
    const int* __restrict__ r_index, const float* __restrict__ qw,
    const float* __restrict__ w1, const float* __restrict__ b1,
    const float* __restrict__ w2, const float* __restrict__ b2,
    float* __restrict__ out) {
    int i = blockIdx.x * blockDim.x + threadIdx.x;
    if (i >= NB * NT) return;
    int b = i / NT;
    int node = t_index[i];
    float feat[2 * ND];
    #pragma unroll
    for (int d = 0; d < ND; ++d)
        feat[d] = hidden[(size_t)b * NN * ND + (size_t)node * ND + d];
    const float* q = qw + r_index[b] * ND;
    #pragma unroll
    for (int d = 0; d < ND; ++d) feat[ND + d] = q[d];
    float acc2 = b2[0];
    for (int j = 0; j < 2 * ND; ++j) {
        float a = b1[j];
        #pragma unroll
        for (int kk = 0; kk < 2 * ND; ++kk) a += feat[kk] * w1[kk * 2 * ND + j];
        acc2 += fmaxf(a, 0.f) * w2[j];
    }
    out[i] = acc2;
}

extern "C" void kernel_launch(void* const* d_in, const int* in_sizes, int n_in,
                              void* d_out, int out_size, void* d_ws, size_t ws_size,
                              hipStream_t stream) {
    (void)in_sizes; (void)n_in; (void)out_size; (void)ws_size;
    const int* edge_index = (const int*)d_in[0];     // [2][E]
    const int* edge_type  = (const int*)d_in[1];     // [E]
    const int* h_index    = (const int*)d_in[2];     // [B]
    const int* r_index    = (const int*)d_in[3];     // [B]
    const int* t_index    = (const int*)d_in[4];     // [B][T]
    const float* query_weight = (const float*)d_in[5];  // [R][D]
    const float* rel_lin_w    = (const float*)d_in[6];  // [L][D][R*D]
    const float* layer_w      = (const float*)d_in[7];  // [L][13D][D]
    const float* layer_b      = (const float*)d_in[8];  // [L][D]
    const float* mlp_w1 = (const float*)d_in[9];
    const float* mlp_b1 = (const float*)d_in[10];
    const float* mlp_w2 = (const float*)d_in[11];
    const float* mlp_b2 = (const float*)d_in[12];
    float* out = (float*)d_out;

    const int* src = edge_index;
    const int* dst = edge_index + NE;

    char* wsp = (char*)d_ws;
    size_t off = 0;
    auto alloc = [&](size_t bytes) -> void* {
        void* p = wsp + off;
        off += (bytes + 255) & ~(size_t)255;
        return p;
    };
    float* h0      = (float*)alloc(sizeof(float) * M_TOT * ND);
    float* h1      = (float*)alloc(sizeof(float) * M_TOT * ND);
    unsigned short* Ah = (unsigned short*)alloc(sizeof(unsigned short) * (size_t)M_TOT * KA);
    unsigned short* Al = (unsigned short*)alloc(sizeof(unsigned short) * (size_t)M_TOT * KA);
    unsigned short* Wph = (unsigned short*)alloc(sizeof(unsigned short) * NL * 2 * 13 * 64 * 8);
    unsigned short* Wpl = (unsigned short*)alloc(sizeof(unsigned short) * NL * 2 * 13 * 64 * 8);
    float* rel     = (float*)alloc(sizeof(float) * NL * NB * NR * ND);
    int2*  csr     = (int2*)alloc(sizeof(int2) * NE);
    int*   offsets = (int*)alloc(sizeof(int) * (NN + 1));
    int*   cursor  = (int*)alloc(sizeof(int) * NN);
    int*   indeg   = (int*)alloc(sizeof(int) * NN);
    float2* scales2 = (float2*)alloc(sizeof(float2) * NN);
    float* ssum    = (float*)alloc(256);

    hipMemsetAsync(indeg, 0, sizeof(int) * NN, stream);
    hipMemsetAsync(cursor, 0, sizeof(int) * NN, stream);
    hipMemsetAsync(ssum, 0, sizeof(float), stream);
    hipMemsetAsync(h0, 0, sizeof(float) * M_TOT * ND, stream);

    count_kernel<<<(NE + 255) / 256, 256, 0, stream>>>(dst, indeg);
    scan_kernel<<<1, 1024, 0, stream>>>(indeg, offsets);
    scatter_kernel<<<(NE + 255) / 256, 256, 0, stream>>>(src, dst, edge_type, offsets, cursor, csr);
    logsum_kernel<<<(NN + 255) / 256, 256, 0, stream>>>(indeg, ssum);
    scales_kernel<<<(NN + 255) / 256, 256, 0, stream>>>(indeg, ssum, scales2);
    init_hidden_kernel<<<1, NB * ND, 0, stream>>>(h0, h_index, r_index, query_weight);

    int rel_total = NL * NB * NR * ND;
    rel_kernel<<<(rel_total + 255) / 256, 256, 0, stream>>>(query_weight, r_index, rel_lin_w, rel);
    wpack_kernel<<<(NL * 2 * 13 * 64 + 255) / 256, 256, 0, stream>>>(layer_w, Wph, Wpl);

    float* hin = h0;
    float* hout = h1;
    for (int l = 0; l < NL; ++l) {
        agg_kernel<<<M_TOT / 16, 512, 0, stream>>>(
            hin, Ah, Al, rel + (size_t)l * NB * NR * ND,
            offsets, csr, h_index, r_index, query_weight);
        gemm_mfma_kernel<<<M_TOT / 16 / 2 / 4 * 2, 256, 0, stream>>>(   // 2500 blocks
            Ah, Al, Wph + (size_t)l * 2 * 13 * 64 * 8, Wpl + (size_t)l * 2 * 13 * 64 * 8,
            hin, hout, layer_b + (size_t)l * ND, scales2);
        float* t = hin; hin = hout; hout = t;
    }
    // final hidden is in `hin`

    score_kernel<<<1, 256, 0, stream>>>(hin, t_index, r_index, query_weight,
                                        mlp_w1, mlp_b1, mlp_w2, mlp_b2, out);
}

// Round 7
// 290.589 us; speedup vs baseline: 2.2382x; 1.0942x over previous
//
#include <hip/hip_runtime.h>
#include <math.h>

#define NN 20000   // nodes
#define NE 480000  // edges
#define NB 4       // batch
#define ND 32      // dim
#define NR 474     // relations
#define NL 3       // layers
#define NT 64      // tails
#define M_TOT (NB * NN)   // 80000 node-rows
#define KA 160            // A columns: h(32) mean(32) mx(32) mn(32) std(32)
#define LROW 168          // padded LDS row (bf16 units) -> <=2-way banks

typedef __attribute__((ext_vector_type(8))) short bf16x8v;
typedef __attribute__((ext_vector_type(4))) float f32x4v;

// RNE split of f32 into bf16 hi + bf16 lo (a ~= hi + lo, err ~2^-18 rel)
__device__ inline void bf16split(float a, unsigned short& h, unsigned short& l) {
    unsigned u = __float_as_uint(a);
    unsigned r = u + 0x7FFFu + ((u >> 16) & 1u);
    h = (unsigned short)(r >> 16);
    float fh = __uint_as_float((unsigned)h << 16);
    float res = a - fh;
    unsigned v = __float_as_uint(res);
    unsigned r2 = v + 0x7FFFu + ((v >> 16) & 1u);
    l = (unsigned short)(r2 >> 16);
}

// ---------------- CSR build ----------------
__global__ __launch_bounds__(256) void count_kernel(const int* __restrict__ dst,
                                                    int* __restrict__ indeg) {
    int e = blockIdx.x * blockDim.x + threadIdx.x;
    if (e < NE) atomicAdd(&indeg[dst[e]], 1);
}

__global__ __launch_bounds__(1024) void scan_kernel(const int* __restrict__ indeg,
                                                    int* __restrict__ offsets) {
    __shared__ int sums[1024];
    int tid = threadIdx.x;
    const int chunk = (NN + 1023) / 1024;  // 20
    int start = tid * chunk;
    int end = start + chunk; if (end > NN) end = NN; if (start > NN) start = NN;
    int s = 0;
    for (int i = start; i < end; ++i) s += indeg[i];
    sums[tid] = s;
    __syncthreads();
    for (int off = 1; off < 1024; off <<= 1) {
        int v = (tid >= off) ? sums[tid - off] : 0;
        __syncthreads();
        sums[tid] += v;
        __syncthreads();
    }
    int base = (tid > 0) ? sums[tid - 1] : 0;
    for (int i = start; i < end; ++i) { offsets[i] = base; base += indeg[i]; }
    if (tid == 1023) offsets[NN] = sums[1023];
}

__global__ __launch_bounds__(256) void scatter_kernel(const int* __restrict__ src,
                                                      const int* __restrict__ dst,
                                                      const int* __restrict__ etype,
                                                      const int* __restrict__ offsets,
                                                      int* __restrict__ cursor,
                                                      int2* __restrict__ csr) {
    int e = blockIdx.x * blockDim.x + threadIdx.x;
    if (e < NE) {
        int dn = dst[e];
        int pos = atomicAdd(&cursor[dn], 1);
        csr[offsets[dn] + pos] = make_int2(src[e], etype[e]);
    }
}

// ---------------- degree-scale sum ----------------
__global__ __launch_bounds__(256) void logsum_kernel(const int* __restrict__ indeg,
                                                     float* __restrict__ ssum) {
    int n = blockIdx.x * blockDim.x + threadIdx.x;
    float v = (n < NN) ? logf((float)(indeg[n] + 2)) : 0.f;  // log(deg+1), deg = indeg+1
    #pragma unroll
    for (int off = 32; off > 0; off >>= 1) v += __shfl_down(v, off, 64);
    if ((threadIdx.x & 63) == 0) atomicAdd(ssum, v);
}

// sc1/sc2 per node, precomputed once
__global__ __launch_bounds__(256) void scales_kernel(const int* __restrict__ indeg,
                                                     const float* __restrict__ ssum,
                                                     float2* __restrict__ scales2) {
    int n = blockIdx.x * blockDim.x + threadIdx.x;
    if (n >= NN) return;
    float scl = logf((float)(indeg[n] + 2)) * ((float)NN / *ssum);
    scales2[n] = make_float2(scl, 1.0f / fmaxf(scl, 1e-2f));
}

// ---------------- boundary init ----------------
__global__ void init_hidden_kernel(float* __restrict__ h0, const int* __restrict__ h_index,
                                   const int* __restrict__ r_index,
                                   const float* __restrict__ qw) {
    int i = threadIdx.x;  // 128 = NB*ND threads
    int b = i >> 5, d = i & 31;
    h0[(size_t)b * NN * ND + (size_t)h_index[b] * ND + d] = qw[r_index[b] * ND + d];
}

// ---------------- per-layer relation embeddings: rel[l][b][r][d] ----------------
__global__ __launch_bounds__(256) void rel_kernel(const float* __restrict__ qw,
                                                  const int* __restrict__ r_index,
                                                  const float* __restrict__ rlw,
                                                  float* __restrict__ rel) {
    int i = blockIdx.x * blockDim.x + threadIdx.x;
    if (i >= NL * NB * NR * ND) return;
    int d = i & (ND - 1);
    int r = (i / ND) % NR;
    int b = (i / (ND * NR)) % NB;
    int l = i / (ND * NR * NB);
    const float* q = qw + r_index[b] * ND;
    const float* w = rlw + (size_t)l * ND * NR * ND + (size_t)r * ND + d;
    float acc = 0.f;
    #pragma unroll
    for (int k = 0; k < ND; ++k) acc += q[k] * w[(size_t)k * NR * ND];
    rel[i] = acc;
}

// ---------------- pack layer_w into MFMA B-fragment layout, bf16 hi/lo ----------------
// Wp[l][nt][s][lane][e]: value = W[l][k][n], k = s*32 + (lane>>4)*8 + e, n = nt*16 + (lane&15)
__global__ __launch_bounds__(256) void wpack_kernel(const float* __restrict__ W,
                                                    unsigned short* __restrict__ Wph,
                                                    unsigned short* __restrict__ Wpl) {
    int t = blockIdx.x * 256 + threadIdx.x;
    if (t >= NL * 2 * 13 * 64) return;
    int lane = t & 63;
    int u = t >> 6;
    int s = u % 13;
    int nt = (u / 13) % 2;
    int l = u / 26;
    int n = nt * 16 + (lane & 15);
    int k0 = s * 32 + (lane >> 4) * 8;
    size_t ob = (size_t)t * 8;
    #pragma unroll
    for (int e = 0; e < 8; ++e) {
        float w = W[(size_t)l * 416 * 32 + (size_t)(k0 + e) * 32 + n];
        unsigned short h8, l8;
        bf16split(w, h8, l8);
        Wph[ob + e] = h8;
        Wpl[ob + e] = l8;
    }
}

// ---------------- fused layer: gather+PNA -> LDS A (bf16 split) -> MFMA update ----------------
// Block = 256 threads = 4 waves, owns 32 node-rows (2 M-tiles; b uniform: 20000%32==0).
// Phase 1: lane = (node r8 = lane>>3, d-quartet d0 = (lane&7)*4); float4 gathers.
// Phase 2: wave w -> C-tile (mt = w>>1, nt = w&1); A-fragments from LDS, B from global (L2).
__global__ __launch_bounds__(256) void layer_fused_kernel(
    const float* __restrict__ hin, float* __restrict__ hnew,
    const float* __restrict__ rel,               // [B][R][D] this layer
    const unsigned short* __restrict__ Wph, const unsigned short* __restrict__ Wpl,
    const float* __restrict__ bias, const float2* __restrict__ scales2,
    const int* __restrict__ offsets, const int2* __restrict__ csr,
    const int* __restrict__ h_index, const int* __restrict__ r_index,
    const float* __restrict__ qw) {
    __shared__ __align__(16) unsigned short ldsAh[32][LROW];
    __shared__ __align__(16) unsigned short ldsAl[32][LROW];

    int tid = threadIdx.x;
    int lane = tid & 63;
    int w = tid >> 6;
    int r8 = lane >> 3;
    int d0 = (lane & 7) * 4;
    int rowl = w * 8 + r8;                       // 0..31
    int idx = blockIdx.x * 32 + rowl;
    int b = idx / NN, n = idx - b * NN;
    const float* hb = hin + (size_t)b * NN * ND;
    const float* relb = rel + (size_t)b * NR * ND;

    // boundary self-message
    float sv[4], ssv[4], mxv[4], mnv[4];
    {
        float4 bm4 = make_float4(0.f, 0.f, 0.f, 0.f);
        if (n == h_index[b]) bm4 = *(const float4*)(qw + r_index[b] * ND + d0);
        float bm[4] = {bm4.x, bm4.y, bm4.z, bm4.w};
        #pragma unroll
        for (int c = 0; c < 4; ++c) {
            sv[c] = bm[c]; ssv[c] = bm[c] * bm[c]; mxv[c] = bm[c]; mnv[c] = bm[c];
        }
    }

    int beg = offsets[n], end = offsets[n + 1];
    int e = beg;
    for (; e + 2 <= end; e += 2) {
        int2 a0 = csr[e], a1 = csr[e + 1];
        float4 h0 = *(const float4*)(hb + (size_t)a0.x * ND + d0);
        float4 r0 = *(const float4*)(relb + (size_t)a0.y * ND + d0);
        float4 h1 = *(const float4*)(hb + (size_t)a1.x * ND + d0);
        float4 r1 = *(const float4*)(relb + (size_t)a1.y * ND + d0);
        float m0[4] = {h0.x * r0.x, h0.y * r0.y, h0.z * r0.z, h0.w * r0.w};
        float m1[4] = {h1.x * r1.x, h1.y * r1.y, h1.z * r1.z, h1.w * r1.w};
        #pragma unroll
        for (int c = 0; c < 4; ++c) {
            sv[c] += m0[c] + m1[c];
            ssv[c] = fmaf(m0[c], m0[c], ssv[c]);
            ssv[c] = fmaf(m1[c], m1[c], ssv[c]);
            mxv[c] = fmaxf(mxv[c], fmaxf(m0[c], m1[c]));
            mnv[c] = fminf(mnv[c], fminf(m0[c], m1[c]));
        }
    }
    if (e < end) {
        int2 a0 = csr[e];
        float4 h0 = *(const float4*)(hb + (size_t)a0.x * ND + d0);
        float4 r0 = *(const float4*)(relb + (size_t)a0.y * ND + d0);
        float m0[4] = {h0.x * r0.x, h0.y * r0.y, h0.z * r0.z, h0.w * r0.w};
        #pragma unroll
        for (int c = 0; c < 4; ++c) {
            sv[c] += m0[c];
            ssv[c] = fmaf(m0[c], m0[c], ssv[c]);
            mxv[c] = fmaxf(mxv[c], m0[c]);
            mnv[c] = fminf(mnv[c], m0[c]);
        }
    }

    float degf = (float)(end - beg + 1);
    float inv = 1.0f / degf;
    float4 h4 = *(const float4*)(hb + (size_t)n * ND + d0);
    float hself[4] = {h4.x, h4.y, h4.z, h4.w};

    // write bf16-split A row to LDS: feats h, mean, mx, mn, std at cols f*32+d0
    #pragma unroll
    for (int f = 0; f < 5; ++f) {
        float vals[4];
        #pragma unroll
        for (int c = 0; c < 4; ++c) {
            float v;
            if (f == 0) v = hself[c];
            else if (f == 1) v = sv[c] * inv;
            else if (f == 2) v = mxv[c];
            else if (f == 3) v = mnv[c];
            else {
                float mean = sv[c] * inv;
                v = sqrtf(fmaxf(ssv[c] * inv - mean * mean, 0.f));
            }
            vals[c] = v;
        }
        ushort4 vh, vl;
        bf16split(vals[0], vh.x, vl.x);
        bf16split(vals[1], vh.y, vl.y);
        bf16split(vals[2], vh.z, vl.z);
        bf16split(vals[3], vh.w, vl.w);
        *(ushort4*)&ldsAh[rowl][f * 32 + d0] = vh;
        *(ushort4*)&ldsAl[rowl][f * 32 + d0] = vl;
    }
    __syncthreads();

    // -------- phase 2: MFMA update --------
    int mt = w >> 1, nt = w & 1;
    int am = lane & 15, kg = lane >> 4;
    int arow = mt * 16 + am;

    bf16x8v ah[5], al[5];
    #pragma unroll
    for (int c = 0; c < 5; ++c) {
        ah[c] = *(const bf16x8v*)&ldsAh[arow][c * 32 + kg * 8];
        al[c] = *(const bf16x8v*)&ldsAl[arow][c * 32 + kg * 8];
    }
    const bf16x8v* Bh = (const bf16x8v*)(Wph + (size_t)nt * 13 * 64 * 8);
    const bf16x8v* Bl = (const bf16x8v*)(Wpl + (size_t)nt * 13 * 64 * 8);

    f32x4v acc_a = {0.f, 0.f, 0.f, 0.f};
    f32x4v acc2  = {0.f, 0.f, 0.f, 0.f};
    f32x4v acc3  = {0.f, 0.f, 0.f, 0.f};

#define GSTEP(S, C, ACC)                                                          \
    {                                                                             \
        bf16x8v bh = Bh[(S) * 64 + lane];                                         \
        bf16x8v bl = Bl[(S) * 64 + lane];                                         \
        ACC = __builtin_amdgcn_mfma_f32_16x16x32_bf16(ah[C], bh, ACC, 0, 0, 0);   \
        ACC = __builtin_amdgcn_mfma_f32_16x16x32_bf16(ah[C], bl, ACC, 0, 0, 0);   \
        ACC = __builtin_amdgcn_mfma_f32_16x16x32_bf16(al[C], bh, ACC, 0, 0, 0);   \
    }
    GSTEP(0, 0, acc_a)
    GSTEP(1, 1, acc_a) GSTEP(2, 2, acc_a) GSTEP(3, 3, acc_a) GSTEP(4, 4, acc_a)
    GSTEP(5, 1, acc2)  GSTEP(6, 2, acc2)  GSTEP(7, 3, acc2)  GSTEP(8, 4, acc2)
    GSTEP(9, 1, acc3)  GSTEP(10, 2, acc3) GSTEP(11, 3, acc3) GSTEP(12, 4, acc3)
#undef GSTEP

    // Epilogue: C layout col = lane&15, row = 4*(lane>>4)+r (verified)
    int j = nt * 16 + am;
    float bj = bias[j];
    #pragma unroll
    for (int r = 0; r < 4; ++r) {
        int i = blockIdx.x * 32 + mt * 16 + 4 * kg + r;
        int nn = i % NN;
        float2 sc = scales2[nn];
        float v = acc_a[r] + sc.x * acc2[r] + sc.y * acc3[r] + bj;
        size_t o = (size_t)i * 32 + j;
        hnew[o] = fmaxf(v, 0.f) + hin[o];
    }
}

// ---------------- final MLP scorer ----------------
__global__ __launch_bounds__(256) void score_kernel(
    const float* __restrict__ hidden, const int* __restrict__ t_index,
    const int* __restrict__ r_index, const float* __restrict__ qw,
    const float* __restrict__ w1, const float* __restrict__ b1,
    const float* __restrict__ w2, const float* __restrict__ b2,
    float* __restrict__ out) {
    int i = blockIdx.x * blockDim.x + threadIdx.x;
    if (i >= NB * NT) return;
    int b = i / NT;
    int node = t_index[i];
    float feat[2 * ND];
    #pragma unroll
    for (int d = 0; d < ND; ++d)
        feat[d] = hidden[(size_t)b * NN * ND + (size_t)node * ND + d];
    const float* q = qw + r_index[b] * ND;
    #pragma unroll
    for (int d = 0; d < ND; ++d) feat[ND + d] = q[d];
    float acc2 = b2[0];
    for (int j = 0; j < 2 * ND; ++j) {
        float a = b1[j];
        #pragma unroll
        for (int kk = 0; kk < 2 * ND; ++kk) a += feat[kk] * w1[kk * 2 * ND + j];
        acc2 += fmaxf(a, 0.f) * w2[j];
    }
    out[i] = acc2;
}

extern "C" void kernel_launch(void* const* d_in, const int* in_sizes, int n_in,
                              void* d_out, int out_size, void* d_ws, size_t ws_size,
                              hipStream_t stream) {
    (void)in_sizes; (void)n_in; (void)out_size; (void)ws_size;
    const int* edge_index = (const int*)d_in[0];     // [2][E]
    const int* edge_type  = (const int*)d_in[1];     // [E]
    const int* h_index    = (const int*)d_in[2];     // [B]
    const int* r_index    = (const int*)d_in[3];     // [B]
    const int* t_index    = (const int*)d_in[4];     // [B][T]
    const float* query_weight = (const float*)d_in[5];  // [R][D]
    const float* rel_lin_w    = (const float*)d_in[6];  // [L][D][R*D]
    const float* layer_w      = (const float*)d_in[7];  // [L][13D][D]
    const float* layer_b      = (const float*)d_in[8];  // [L][D]
    const float* mlp_w1 = (const float*)d_in[9];
    const float* mlp_b1 = (const float*)d_in[10];
    const float* mlp_w2 = (const float*)d_in[11];
    const float* mlp_b2 = (const float*)d_in[12];
    float* out = (float*)d_out;

    const int* src = edge_index;
    const int* dst = edge_index + NE;

    char* wsp = (char*)d_ws;
    size_t off = 0;
    auto alloc = [&](size_t bytes) -> void* {
        void* p = wsp + off;
        off += (bytes + 255) & ~(size_t)255;
        return p;
    };
    float* h0      = (float*)alloc(sizeof(float) * M_TOT * ND);
    float* h1      = (float*)alloc(sizeof(float) * M_TOT * ND);
    unsigned short* Wph = (unsigned short*)alloc(sizeof(unsigned short) * NL * 2 * 13 * 64 * 8);
    unsigned short* Wpl = (unsigned short*)alloc(sizeof(unsigned short) * NL * 2 * 13 * 64 * 8);
    float* rel     = (float*)alloc(sizeof(float) * NL * NB * NR * ND);
    int2*  csr     = (int2*)alloc(sizeof(int2) * NE);
    int*   offsets = (int*)alloc(sizeof(int) * (NN + 1));
    int*   cursor  = (int*)alloc(sizeof(int) * NN);
    int*   indeg   = (int*)alloc(sizeof(int) * NN);
    float2* scales2 = (float2*)alloc(sizeof(float2) * NN);
    float* ssum    = (float*)alloc(256);

    hipMemsetAsync(indeg, 0, sizeof(int) * NN, stream);
    hipMemsetAsync(cursor, 0, sizeof(int) * NN, stream);
    hipMemsetAsync(ssum, 0, sizeof(float), stream);
    hipMemsetAsync(h0, 0, sizeof(float) * M_TOT * ND, stream);

    count_kernel<<<(NE + 255) / 256, 256, 0, stream>>>(dst, indeg);
    scan_kernel<<<1, 1024, 0, stream>>>(indeg, offsets);
    scatter_kernel<<<(NE + 255) / 256, 256, 0, stream>>>(src, dst, edge_type, offsets, cursor, csr);
    logsum_kernel<<<(NN + 255) / 256, 256, 0, stream>>>(indeg, ssum);
    scales_kernel<<<(NN + 255) / 256, 256, 0, stream>>>(indeg, ssum, scales2);
    init_hidden_kernel<<<1, NB * ND, 0, stream>>>(h0, h_index, r_index, query_weight);

    int rel_total = NL * NB * NR * ND;
    rel_kernel<<<(rel_total + 255) / 256, 256, 0, stream>>>(query_weight, r_index, rel_lin_w, rel);
    wpack_kernel<<<(NL * 2 * 13 * 64 + 255) / 256, 256, 0, stream>>>(layer_w, Wph, Wpl);

    float* hin = h0;
    float* hout = h1;
    for (int l = 0; l < NL; ++l) {
        layer_fused_kernel<<<M_TOT / 32, 256, 0, stream>>>(
            hin, hout, rel + (size_t)l * NB * NR * ND,
            Wph + (size_t)l * 2 * 13 * 64 * 8, Wpl + (size_t)l * 2 * 13 * 64 * 8,
            layer_b + (size_t)l * ND, scales2,
            offsets, csr, h_index, r_index, query_weight);
        float* t = hin; hin = hout; hout = t;
    }
    // final hidden is in `hin`

    score_kernel<<<1, 256, 0, stream>>>(hin, t_index, r_index, query_weight,
                                        mlp_w1, mlp_b1, mlp_w2, mlp_b2, out);
}

// Round 8
// 274.848 us; speedup vs baseline: 2.3664x; 1.0573x over previous
//
#include <hip/hip_runtime.h>
#include <math.h>

#define NN 20000   // nodes
#define NE 480000  // edges
#define NB 4       // batch
#define ND 32      // dim
#define NR 474     // relations
#define NL 3       // layers
#define NT 64      // tails
#define M_TOT (NB * NN)   // 80000 node-rows
#define KA 160            // A columns: h(32) mean(32) mx(32) mn(32) std(32)
#define LROW 168          // padded LDS row (bf16 units)

typedef __attribute__((ext_vector_type(8))) short bf16x8v;
typedef __attribute__((ext_vector_type(4))) float f32x4v;

// RNE split of f32 into bf16 hi + bf16 lo (a ~= hi + lo, err ~2^-18 rel)
__device__ inline void bf16split(float a, unsigned short& h, unsigned short& l) {
    unsigned u = __float_as_uint(a);
    unsigned r = u + 0x7FFFu + ((u >> 16) & 1u);
    h = (unsigned short)(r >> 16);
    float fh = __uint_as_float((unsigned)h << 16);
    float res = a - fh;
    unsigned v = __float_as_uint(res);
    unsigned r2 = v + 0x7FFFu + ((v >> 16) & 1u);
    l = (unsigned short)(r2 >> 16);
}

// ---------------- CSR build ----------------
__global__ __launch_bounds__(256) void count_kernel(const int* __restrict__ dst,
                                                    int* __restrict__ indeg) {
    int e = blockIdx.x * blockDim.x + threadIdx.x;
    if (e < NE) atomicAdd(&indeg[dst[e]], 1);
}

// scan + log-degree normalization + PNA scales + boundary init, one 1-block kernel
__global__ __launch_bounds__(1024) void scan_fused_kernel(
    const int* __restrict__ indeg, int* __restrict__ offsets,
    float2* __restrict__ scales2, float* __restrict__ h0,
    const int* __restrict__ h_index, const int* __restrict__ r_index,
    const float* __restrict__ qw) {
    __shared__ int sums[1024];
    __shared__ float lsums[1024];
    int tid = threadIdx.x;
    const int chunk = (NN + 1023) / 1024;  // 20
    int start = tid * chunk;
    int end = start + chunk; if (end > NN) end = NN; if (start > NN) start = NN;
    int s = 0; float ls = 0.f;
    for (int i = start; i < end; ++i) {
        s += indeg[i];
        ls += logf((float)(indeg[i] + 2));   // log(deg+1), deg = indeg+1
    }
    sums[tid] = s; lsums[tid] = ls;
    __syncthreads();
    for (int off = 1; off < 1024; off <<= 1) {
        int v = (tid >= off) ? sums[tid - off] : 0;
        float lv = (tid >= off) ? lsums[tid - off] : 0.f;
        __syncthreads();
        sums[tid] += v; lsums[tid] += lv;
        __syncthreads();
    }
    float fac = (float)NN / lsums[1023];
    int base = (tid > 0) ? sums[tid - 1] : 0;
    for (int i = start; i < end; ++i) {
        offsets[i] = base; base += indeg[i];
        float scl = logf((float)(indeg[i] + 2)) * fac;
        scales2[i] = make_float2(scl, 1.0f / fmaxf(scl, 1e-2f));
    }
    if (tid == 1023) offsets[NN] = sums[1023];
    if (tid < NB * ND) {                      // boundary init (h0 pre-zeroed)
        int b = tid >> 5, d = tid & 31;
        h0[(size_t)b * NN * ND + (size_t)h_index[b] * ND + d] = qw[r_index[b] * ND + d];
    }
}

__global__ __launch_bounds__(256) void scatter_kernel(const int* __restrict__ src,
                                                      const int* __restrict__ dst,
                                                      const int* __restrict__ etype,
                                                      const int* __restrict__ offsets,
                                                      int* __restrict__ cursor,
                                                      int2* __restrict__ csr) {
    int e = blockIdx.x * blockDim.x + threadIdx.x;
    if (e < NE) {
        int dn = dst[e];
        int pos = atomicAdd(&cursor[dn], 1);
        csr[offsets[dn] + pos] = make_int2(src[e], etype[e]);
    }
}

// ---------------- rel embeddings + W pack, one kernel ----------------
// blocks [0, 711): rel[l][b][r][d];  blocks [711, 731): Wp pack
#define REL_BLOCKS 711
__global__ __launch_bounds__(256) void relwpack_kernel(
    const float* __restrict__ qw, const int* __restrict__ r_index,
    const float* __restrict__ rlw, float* __restrict__ rel,
    const float* __restrict__ W, unsigned short* __restrict__ Wph,
    unsigned short* __restrict__ Wpl) {
    if (blockIdx.x < REL_BLOCKS) {
        int i = blockIdx.x * 256 + threadIdx.x;   // < 182016 always
        int d = i & (ND - 1);
        int r = (i / ND) % NR;
        int b = (i / (ND * NR)) % NB;
        int l = i / (ND * NR * NB);
        const float* q = qw + r_index[b] * ND;
        const float* w = rlw + (size_t)l * ND * NR * ND + (size_t)r * ND + d;
        float acc = 0.f;
        #pragma unroll
        for (int k = 0; k < ND; ++k) acc += q[k] * w[(size_t)k * NR * ND];
        rel[i] = acc;
    } else {
        int t = (blockIdx.x - REL_BLOCKS) * 256 + threadIdx.x;
        if (t >= NL * 2 * 13 * 64) return;
        int lane = t & 63;
        int u = t >> 6;
        int s = u % 13;
        int nt = (u / 13) % 2;
        int l = u / 26;
        int n = nt * 16 + (lane & 15);
        int k0 = s * 32 + (lane >> 4) * 8;
        size_t ob = (size_t)t * 8;
        #pragma unroll
        for (int e = 0; e < 8; ++e) {
            float w = W[(size_t)l * 416 * 32 + (size_t)(k0 + e) * 32 + n];
            unsigned short h8, l8;
            bf16split(w, h8, l8);
            Wph[ob + e] = h8;
            Wpl[ob + e] = l8;
        }
    }
}

// ---------------- fused layer: gather+PNA -> LDS A (bf16 split) -> MFMA update ----------------
// Block = 256 threads = 4 waves, owns 32 node-rows of ONE batch (20000%32==0 -> b uniform).
// XCD-chunked bijective swizzle: each XCD gets a contiguous logical range -> its L2
// holds only ~1 batch's hidden (2.6MB < 4MB). Edge loop unrolled x4 (int4 csr loads).
__global__ __launch_bounds__(256) void layer_fused_kernel(
    const float* __restrict__ hin, float* __restrict__ hnew,
    const float* __restrict__ rel,               // [B][R][D] this layer
    const unsigned short* __restrict__ Wph, const unsigned short* __restrict__ Wpl,
    const float* __restrict__ bias, const float2* __restrict__ scales2,
    const int* __restrict__ offsets, const int2* __restrict__ csr,
    const int* __restrict__ h_index, const int* __restrict__ r_index,
    const float* __restrict__ qw) {
    __shared__ __align__(16) unsigned short ldsAh[32][LROW];
    __shared__ __align__(16) unsigned short ldsAl[32][LROW];

    // bijective XCD swizzle (NWG = 2500 = 8*312 + 4)
    const int NWG = M_TOT / 32, q = NWG >> 3, r = NWG & 7;
    int p = blockIdx.x;
    int x = p & 7, pos = p >> 3;
    const int blk = (x < r ? x * (q + 1) : r * (q + 1) + (x - r) * q) + pos;

    int tid = threadIdx.x;
    int lane = tid & 63;
    int w = tid >> 6;
    int r8 = lane >> 3;
    int d0 = (lane & 7) * 4;
    int rowl = w * 8 + r8;                       // 0..31
    int idx = blk * 32 + rowl;
    int b = idx / NN, n = idx - b * NN;
    const float* hb = hin + (size_t)b * NN * ND;
    const float* relb = rel + (size_t)b * NR * ND;

    float sv[4], ssv[4], mxv[4], mnv[4];
    {
        float4 bm4 = make_float4(0.f, 0.f, 0.f, 0.f);
        if (n == h_index[b]) bm4 = *(const float4*)(qw + r_index[b] * ND + d0);
        float bm[4] = {bm4.x, bm4.y, bm4.z, bm4.w};
        #pragma unroll
        for (int c = 0; c < 4; ++c) {
            sv[c] = bm[c]; ssv[c] = bm[c] * bm[c]; mxv[c] = bm[c]; mnv[c] = bm[c];
        }
    }

    int beg = offsets[n], end = offsets[n + 1];
    int e = beg;
#define EDGE1(E)                                                                  \
    {                                                                             \
        int2 a0 = csr[E];                                                         \
        float4 h0 = *(const float4*)(hb + (size_t)a0.x * ND + d0);                \
        float4 r0 = *(const float4*)(relb + (size_t)a0.y * ND + d0);              \
        float m0[4] = {h0.x * r0.x, h0.y * r0.y, h0.z * r0.z, h0.w * r0.w};       \
        _Pragma("unroll")                                                         \
        for (int c = 0; c < 4; ++c) {                                             \
            sv[c] += m0[c];                                                       \
            ssv[c] = fmaf(m0[c], m0[c], ssv[c]);                                  \
            mxv[c] = fmaxf(mxv[c], m0[c]);                                        \
            mnv[c] = fminf(mnv[c], m0[c]);                                        \
        }                                                                         \
    }
    if ((e & 1) && e < end) { EDGE1(e); ++e; }       // align to 16B for int4 loads
    for (; e + 4 <= end; e += 4) {
        int4 c01 = *(const int4*)(csr + e);          // (s0,t0,s1,t1)
        int4 c23 = *(const int4*)(csr + e + 2);      // (s2,t2,s3,t3)
        float4 h0 = *(const float4*)(hb + (size_t)c01.x * ND + d0);
        float4 r0 = *(const float4*)(relb + (size_t)c01.y * ND + d0);
        float4 h1 = *(const float4*)(hb + (size_t)c01.z * ND + d0);
        float4 r1 = *(const float4*)(relb + (size_t)c01.w * ND + d0);
        float4 h2 = *(const float4*)(hb + (size_t)c23.x * ND + d0);
        float4 r2 = *(const float4*)(relb + (size_t)c23.y * ND + d0);
        float4 h3 = *(const float4*)(hb + (size_t)c23.z * ND + d0);
        float4 r3 = *(const float4*)(relb + (size_t)c23.w * ND + d0);
        float m0[4] = {h0.x * r0.x, h0.y * r0.y, h0.z * r0.z, h0.w * r0.w};
        float m1[4] = {h1.x * r1.x, h1.y * r1.y, h1.z * r1.z, h1.w * r1.w};
        float m2[4] = {h2.x * r2.x, h2.y * r2.y, h2.z * r2.z, h2.w * r2.w};
        float m3[4] = {h3.x * r3.x, h3.y * r3.y, h3.z * r3.z, h3.w * r3.w};
        #pragma unroll
        for (int c = 0; c < 4; ++c) {
            sv[c] += (m0[c] + m1[c]) + (m2[c] + m3[c]);
            ssv[c] = fmaf(m0[c], m0[c], ssv[c]);
            ssv[c] = fmaf(m1[c], m1[c], ssv[c]);
            ssv[c] = fmaf(m2[c], m2[c], ssv[c]);
            ssv[c] = fmaf(m3[c], m3[c], ssv[c]);
            mxv[c] = fmaxf(mxv[c], fmaxf(fmaxf(m0[c], m1[c]), fmaxf(m2[c], m3[c])));
            mnv[c] = fminf(mnv[c], fminf(fminf(m0[c], m1[c]), fminf(m2[c], m3[c])));
        }
    }
    for (; e < end; ++e) EDGE1(e);
#undef EDGE1

    float degf = (float)(end - beg + 1);
    float inv = 1.0f / degf;
    float4 h4 = *(const float4*)(hb + (size_t)n * ND + d0);
    float hself[4] = {h4.x, h4.y, h4.z, h4.w};

    #pragma unroll
    for (int f = 0; f < 5; ++f) {
        float vals[4];
        #pragma unroll
        for (int c = 0; c < 4; ++c) {
            float v;
            if (f == 0) v = hself[c];
            else if (f == 1) v = sv[c] * inv;
            else if (f == 2) v = mxv[c];
            else if (f == 3) v = mnv[c];
            else {
                float mean = sv[c] * inv;
                v = sqrtf(fmaxf(ssv[c] * inv - mean * mean, 0.f));
            }
            vals[c] = v;
        }
        ushort4 vh, vl;
        bf16split(vals[0], vh.x, vl.x);
        bf16split(vals[1], vh.y, vl.y);
        bf16split(vals[2], vh.z, vl.z);
        bf16split(vals[3], vh.w, vl.w);
        *(ushort4*)&ldsAh[rowl][f * 32 + d0] = vh;
        *(ushort4*)&ldsAl[rowl][f * 32 + d0] = vl;
    }
    __syncthreads();

    // -------- phase 2: MFMA update --------
    int mt = w >> 1, nt = w & 1;
    int am = lane & 15, kg = lane >> 4;
    int arow = mt * 16 + am;

    bf16x8v ah[5], al[5];
    #pragma unroll
    for (int c = 0; c < 5; ++c) {
        ah[c] = *(const bf16x8v*)&ldsAh[arow][c * 32 + kg * 8];
        al[c] = *(const bf16x8v*)&ldsAl[arow][c * 32 + kg * 8];
    }
    const bf16x8v* Bh = (const bf16x8v*)(Wph + (size_t)nt * 13 * 64 * 8);
    const bf16x8v* Bl = (const bf16x8v*)(Wpl + (size_t)nt * 13 * 64 * 8);

    f32x4v acc_a = {0.f, 0.f, 0.f, 0.f};
    f32x4v acc2  = {0.f, 0.f, 0.f, 0.f};
    f32x4v acc3  = {0.f, 0.f, 0.f, 0.f};

#define GSTEP(S, C, ACC)                                                          \
    {                                                                             \
        bf16x8v bh = Bh[(S) * 64 + lane];                                         \
        bf16x8v bl = Bl[(S) * 64 + lane];                                         \
        ACC = __builtin_amdgcn_mfma_f32_16x16x32_bf16(ah[C], bh, ACC, 0, 0, 0);   \
        ACC = __builtin_amdgcn_mfma_f32_16x16x32_bf16(ah[C], bl, ACC, 0, 0, 0);   \
        ACC = __builtin_amdgcn_mfma_f32_16x16x32_bf16(al[C], bh, ACC, 0, 0, 0);   \
    }
    GSTEP(0, 0, acc_a)
    GSTEP(1, 1, acc_a) GSTEP(2, 2, acc_a) GSTEP(3, 3, acc_a) GSTEP(4, 4, acc_a)
    GSTEP(5, 1, acc2)  GSTEP(6, 2, acc2)  GSTEP(7, 3, acc2)  GSTEP(8, 4, acc2)
    GSTEP(9, 1, acc3)  GSTEP(10, 2, acc3) GSTEP(11, 3, acc3) GSTEP(12, 4, acc3)
#undef GSTEP

    // Epilogue: C layout col = lane&15, row = 4*(lane>>4)+r (verified)
    int j = nt * 16 + am;
    float bj = bias[j];
    #pragma unroll
    for (int rr = 0; rr < 4; ++rr) {
        int i = blk * 32 + mt * 16 + 4 * kg + rr;
        int nn = i % NN;
        float2 sc = scales2[nn];
        float v = acc_a[rr] + sc.x * acc2[rr] + sc.y * acc3[rr] + bj;
        size_t o = (size_t)i * 32 + j;
        hnew[o] = fmaxf(v, 0.f) + hin[o];
    }
}

// ---------------- final MLP scorer ----------------
__global__ __launch_bounds__(256) void score_kernel(
    const float* __restrict__ hidden, const int* __restrict__ t_index,
    const int* __restrict__ r_index, const float* __restrict__ qw,
    const float* __restrict__ w1, const float* __restrict__ b1,
    const float* __restrict__ w2, const float* __restrict__ b2,
    float* __restrict__ out) {
    int i = blockIdx.x * blockDim.x + threadIdx.x;
    if (i >= NB * NT) return;
    int b = i / NT;
    int node = t_index[i];
    float feat[2 * ND];
    #pragma unroll
    for (int d = 0; d < ND; ++d)
        feat[d] = hidden[(size_t)b * NN * ND + (size_t)node * ND + d];
    const float* q = qw + r_index[b] * ND;
    #pragma unroll
    for (int d = 0; d < ND; ++d) feat[ND + d] = q[d];
    float acc2 = b2[0];
    for (int j = 0; j < 2 * ND; ++j) {
        float a = b1[j];
        #pragma unroll
        for (int kk = 0; kk < 2 * ND; ++kk) a += feat[kk] * w1[kk * 2 * ND + j];
        acc2 += fmaxf(a, 0.f) * w2[j];
    }
    out[i] = acc2;
}

extern "C" void kernel_launch(void* const* d_in, const int* in_sizes, int n_in,
                              void* d_out, int out_size, void* d_ws, size_t ws_size,
                              hipStream_t stream) {
    (void)in_sizes; (void)n_in; (void)out_size; (void)ws_size;
    const int* edge_index = (const int*)d_in[0];     // [2][E]
    const int* edge_type  = (const int*)d_in[1];     // [E]
    const int* h_index    = (const int*)d_in[2];     // [B]
    const int* r_index    = (const int*)d_in[3];     // [B]
    const int* t_index    = (const int*)d_in[4];     // [B][T]
    const float* query_weight = (const float*)d_in[5];  // [R][D]
    const float* rel_lin_w    = (const float*)d_in[6];  // [L][D][R*D]
    const float* layer_w      = (const float*)d_in[7];  // [L][13D][D]
    const float* layer_b      = (const float*)d_in[8];  // [L][D]
    const float* mlp_w1 = (const float*)d_in[9];
    const float* mlp_b1 = (const float*)d_in[10];
    const float* mlp_w2 = (const float*)d_in[11];
    const float* mlp_b2 = (const float*)d_in[12];
    float* out = (float*)d_out;

    const int* src = edge_index;
    const int* dst = edge_index + NE;

    char* wsp = (char*)d_ws;
    size_t off = 0;
    auto alloc = [&](size_t bytes) -> void* {
        void* p = wsp + off;
        off += (bytes + 255) & ~(size_t)255;
        return p;
    };
    float* h0      = (float*)alloc(sizeof(float) * M_TOT * ND);
    float* h1      = (float*)alloc(sizeof(float) * M_TOT * ND);
    unsigned short* Wph = (unsigned short*)alloc(sizeof(unsigned short) * NL * 2 * 13 * 64 * 8);
    unsigned short* Wpl = (unsigned short*)alloc(sizeof(unsigned short) * NL * 2 * 13 * 64 * 8);
    float* rel     = (float*)alloc(sizeof(float) * NL * NB * NR * ND);
    int2*  csr     = (int2*)alloc(sizeof(int2) * NE);
    int*   offsets = (int*)alloc(sizeof(int) * (NN + 1));
    int*   cursor  = (int*)alloc(sizeof(int) * NN);
    int*   indeg   = (int*)alloc(sizeof(int) * NN);
    float2* scales2 = (float2*)alloc(sizeof(float2) * NN);

    hipMemsetAsync(indeg, 0, sizeof(int) * NN, stream);
    hipMemsetAsync(cursor, 0, sizeof(int) * NN, stream);
    hipMemsetAsync(h0, 0, sizeof(float) * M_TOT * ND, stream);

    count_kernel<<<(NE + 255) / 256, 256, 0, stream>>>(dst, indeg);
    scan_fused_kernel<<<1, 1024, 0, stream>>>(indeg, offsets, scales2, h0,
                                              h_index, r_index, query_weight);
    scatter_kernel<<<(NE + 255) / 256, 256, 0, stream>>>(src, dst, edge_type, offsets, cursor, csr);
    relwpack_kernel<<<REL_BLOCKS + (NL * 2 * 13 * 64 + 255) / 256, 256, 0, stream>>>(
        query_weight, r_index, rel_lin_w, rel, layer_w, Wph, Wpl);

    float* hin = h0;
    float* hout = h1;
    for (int l = 0; l < NL; ++l) {
        layer_fused_kernel<<<M_TOT / 32, 256, 0, stream>>>(
            hin, hout, rel + (size_t)l * NB * NR * ND,
            Wph + (size_t)l * 2 * 13 * 64 * 8, Wpl + (size_t)l * 2 * 13 * 64 * 8,
            layer_b + (size_t)l * ND, scales2,
            offsets, csr, h_index, r_index, query_weight);
        float* t = hin; hin = hout; hout = t;
    }
    // final hidden is in `hin`

    score_kernel<<<1, 256, 0, stream>>>(hin, t_index, r_index, query_weight,
                                        mlp_w1, mlp_b1, mlp_w2, mlp_b2, out);
}

// Round 9
// 252.918 us; speedup vs baseline: 2.5716x; 1.0867x over previous
//
#include <hip/hip_runtime.h>
#include <math.h>

#define NN 20000   // nodes
#define NE 480000  // edges
#define NB 4       // batch
#define ND 32      // dim
#define NR 474     // relations
#define NL 3       // layers
#define NT 64      // tails
#define M_TOT (NB * NN)   // 80000 node-rows
#define LROW 168          // padded LDS row (bf16 units); 336B = 21x16B -> conflict-free b128

typedef __attribute__((ext_vector_type(8))) short bf16x8v;
typedef __attribute__((ext_vector_type(4))) float f32x4v;

// RNE split of f32 into bf16 hi + bf16 lo (a ~= hi + lo, err ~2^-18 rel)
__device__ inline void bf16split(float a, unsigned short& h, unsigned short& l) {
    unsigned u = __float_as_uint(a);
    unsigned r = u + 0x7FFFu + ((u >> 16) & 1u);
    h = (unsigned short)(r >> 16);
    float fh = __uint_as_float((unsigned)h << 16);
    float res = a - fh;
    unsigned v = __float_as_uint(res);
    unsigned r2 = v + 0x7FFFu + ((v >> 16) & 1u);
    l = (unsigned short)(r2 >> 16);
}

// ---------------- CSR build ----------------
__global__ __launch_bounds__(256) void count_kernel(const int* __restrict__ dst,
                                                    int* __restrict__ indeg) {
    int e = blockIdx.x * blockDim.x + threadIdx.x;
    if (e < NE) atomicAdd(&indeg[dst[e]], 1);
}

// scan + log-degree scales + boundary init + degree-bucket sort (perm), one 1-block kernel
__global__ __launch_bounds__(1024) void scan_fused_kernel(
    const int* __restrict__ indeg, int* __restrict__ offsets,
    float2* __restrict__ scales2, float* __restrict__ h0,
    int* __restrict__ perm,
    const int* __restrict__ h_index, const int* __restrict__ r_index,
    const float* __restrict__ qw) {
    __shared__ int sums[1024];
    __shared__ float lsums[1024];
    __shared__ int whist[16][256];   // per-wave degree histogram
    __shared__ int gbase[256];
    int tid = threadIdx.x;
    int wid = tid >> 6;
    for (int i = tid; i < 16 * 256; i += 1024) ((int*)whist)[i] = 0;
    __syncthreads();

    const int chunk = (NN + 1023) / 1024;  // 20
    int start = tid * chunk;
    int end = start + chunk; if (end > NN) end = NN; if (start > NN) start = NN;
    int s = 0; float ls = 0.f;
    for (int i = start; i < end; ++i) {
        int dg = indeg[i];
        s += dg;
        ls += logf((float)(dg + 2));   // log(deg+1), deg = indeg+1
        int bkt = dg > 255 ? 255 : dg;
        atomicAdd(&whist[wid][bkt], 1);
    }
    sums[tid] = s; lsums[tid] = ls;
    __syncthreads();
    for (int off = 1; off < 1024; off <<= 1) {
        int v = (tid >= off) ? sums[tid - off] : 0;
        float lv = (tid >= off) ? lsums[tid - off] : 0.f;
        __syncthreads();
        sums[tid] += v; lsums[tid] += lv;
        __syncthreads();
    }
    // per-bucket: turn whist into intra-bucket per-wave exclusive offsets; gbase = bucket totals
    if (tid < 256) {
        int running = 0;
        #pragma unroll
        for (int w = 0; w < 16; ++w) { int t = whist[w][tid]; whist[w][tid] = running; running += t; }
        gbase[tid] = running;
    }
    __syncthreads();
    // inclusive prefix over bucket totals
    for (int off = 1; off < 256; off <<= 1) {
        int v = 0;
        if (tid < 256 && tid >= off) v = gbase[tid - off];
        __syncthreads();
        if (tid < 256) gbase[tid] += v;
        __syncthreads();
    }
    if (tid < 256) {
        int ex = (tid > 0) ? gbase[tid - 1] : 0;  // exclusive bucket base
        #pragma unroll
        for (int w = 0; w < 16; ++w) whist[w][tid] += ex;
    }
    __syncthreads();

    float fac = (float)NN / lsums[1023];
    int base = (tid > 0) ? sums[tid - 1] : 0;
    for (int i = start; i < end; ++i) {
        int dg = indeg[i];
        offsets[i] = base; base += dg;
        float scl = logf((float)(dg + 2)) * fac;
        scales2[i] = make_float2(scl, 1.0f / fmaxf(scl, 1e-2f));
        int bkt = dg > 255 ? 255 : dg;
        int pos = atomicAdd(&whist[wid][bkt], 1);
        perm[pos] = i;
    }
    if (tid == 1023) offsets[NN] = sums[1023];
    if (tid < NB * ND) {                      // boundary init (h0 pre-zeroed)
        int b = tid >> 5, d = tid & 31;
        h0[(size_t)b * NN * ND + (size_t)h_index[b] * ND + d] = qw[r_index[b] * ND + d];
    }
}

// csr entries hold BYTE offsets: (src*128, etype*128) -> int32 addressing in gather
__global__ __launch_bounds__(256) void scatter_kernel(const int* __restrict__ src,
                                                      const int* __restrict__ dst,
                                                      const int* __restrict__ etype,
                                                      const int* __restrict__ offsets,
                                                      int* __restrict__ cursor,
                                                      int2* __restrict__ csr) {
    int e = blockIdx.x * blockDim.x + threadIdx.x;
    if (e < NE) {
        int dn = dst[e];
        int pos = atomicAdd(&cursor[dn], 1);
        csr[offsets[dn] + pos] = make_int2(src[e] * (ND * 4), etype[e] * (ND * 4));
    }
}

// ---------------- rel embeddings (4 batches/thread) + W pack, one kernel ----------------
#define REL_T (NL * NR * ND)              // 45504
#define REL_BLOCKS ((REL_T + 255) / 256)  // 178
__global__ __launch_bounds__(256) void relwpack_kernel(
    const float* __restrict__ qw, const int* __restrict__ r_index,
    const float* __restrict__ rlw, float* __restrict__ rel,
    const float* __restrict__ W, unsigned short* __restrict__ Wph,
    unsigned short* __restrict__ Wpl) {
    if (blockIdx.x < REL_BLOCKS) {
        int i = blockIdx.x * 256 + threadIdx.x;
        if (i >= REL_T) return;
        int d = i & (ND - 1);
        int rd = i >> 5;
        int r = rd % NR;
        int l = rd / NR;
        const float* q0 = qw + r_index[0] * ND;
        const float* q1 = qw + r_index[1] * ND;
        const float* q2 = qw + r_index[2] * ND;
        const float* q3 = qw + r_index[3] * ND;
        const float* w = rlw + (size_t)l * ND * NR * ND + (size_t)r * ND + d;
        float a0 = 0.f, a1 = 0.f, a2 = 0.f, a3 = 0.f;
        #pragma unroll
        for (int k = 0; k < ND; ++k) {
            float wk = w[(size_t)k * NR * ND];
            a0 = fmaf(q0[k], wk, a0); a1 = fmaf(q1[k], wk, a1);
            a2 = fmaf(q2[k], wk, a2); a3 = fmaf(q3[k], wk, a3);
        }
        size_t o = ((size_t)l * NB * NR + r) * ND + d;
        rel[o] = a0;
        rel[o + (size_t)NR * ND] = a1;
        rel[o + (size_t)2 * NR * ND] = a2;
        rel[o + (size_t)3 * NR * ND] = a3;
    } else {
        int t = (blockIdx.x - REL_BLOCKS) * 256 + threadIdx.x;
        if (t >= NL * 2 * 13 * 64) return;
        int lane = t & 63;
        int u = t >> 6;
        int s = u % 13;
        int nt = (u / 13) % 2;
        int l = u / 26;
        int n = nt * 16 + (lane & 15);
        int k0 = s * 32 + (lane >> 4) * 8;
        size_t ob = (size_t)t * 8;
        #pragma unroll
        for (int e = 0; e < 8; ++e) {
            float w = W[(size_t)l * 416 * 32 + (size_t)(k0 + e) * 32 + n];
            unsigned short h8, l8;
            bf16split(w, h8, l8);
            Wph[ob + e] = h8;
            Wpl[ob + e] = l8;
        }
    }
}

// ---------------- fused layer: gather+PNA -> LDS A (bf16 split) -> MFMA update ----------------
// Rows are degree-sorted (perm) -> the 8 nodes of a wave have near-equal degree.
// Block = 256 threads = 4 waves, 32 sorted rows of ONE batch. XCD-chunked bijective swizzle.
__global__ __launch_bounds__(256) void layer_fused_kernel(
    const float* __restrict__ hin, float* __restrict__ hnew,
    const float* __restrict__ rel,               // [B][R][D] this layer
    const unsigned short* __restrict__ Wph, const unsigned short* __restrict__ Wpl,
    const float* __restrict__ bias, const float2* __restrict__ scales2,
    const int* __restrict__ offsets, const int2* __restrict__ csr,
    const int* __restrict__ perm,
    const int* __restrict__ h_index, const int* __restrict__ r_index,
    const float* __restrict__ qw) {
    __shared__ __align__(16) unsigned short ldsAh[32][LROW];
    __shared__ __align__(16) unsigned short ldsAl[32][LROW];

    // bijective XCD swizzle (NWG = 2500 = 8*312 + 4)
    const int NWG = M_TOT / 32, q = NWG >> 3, r = NWG & 7;
    int p = blockIdx.x;
    int x = p & 7, pos = p >> 3;
    const int blk = (x < r ? x * (q + 1) : r * (q + 1) + (x - r) * q) + pos;

    int tid = threadIdx.x;
    int lane = tid & 63;
    int w = tid >> 6;
    int r8 = lane >> 3;
    int d0 = (lane & 7) * 4;                     // dim quartet
    int d4 = d0 * 4;                             // byte offset
    int rowl = w * 8 + r8;                       // 0..31
    int idx = blk * 32 + rowl;
    int b = idx / NN;                            // block-uniform
    int sidx = idx - b * NN;
    int n = perm[sidx];
    const char* hbB = (const char*)hin + (size_t)b * (NN * ND * 4) + d4;
    const char* reB = (const char*)rel + (size_t)b * (NR * ND * 4) + d4;

    float sv[4], ssv[4], mxv[4], mnv[4];
    {
        float4 bm4 = make_float4(0.f, 0.f, 0.f, 0.f);
        if (n == h_index[b]) bm4 = *(const float4*)(qw + r_index[b] * ND + d0);
        float bm[4] = {bm4.x, bm4.y, bm4.z, bm4.w};
        #pragma unroll
        for (int c = 0; c < 4; ++c) {
            sv[c] = bm[c]; ssv[c] = bm[c] * bm[c]; mxv[c] = bm[c]; mnv[c] = bm[c];
        }
    }

    int beg = offsets[n], end = offsets[n + 1];
    int e = beg;
#define EDGE1(E)                                                                  \
    {                                                                             \
        int2 a0 = csr[E];                                                         \
        float4 h0 = *(const float4*)(hbB + a0.x);                                 \
        float4 r0 = *(const float4*)(reB + a0.y);                                 \
        float m0[4] = {h0.x * r0.x, h0.y * r0.y, h0.z * r0.z, h0.w * r0.w};       \
        _Pragma("unroll")                                                         \
        for (int c = 0; c < 4; ++c) {                                             \
            sv[c] += m0[c];                                                       \
            ssv[c] = fmaf(m0[c], m0[c], ssv[c]);                                  \
            mxv[c] = fmaxf(mxv[c], m0[c]);                                        \
            mnv[c] = fminf(mnv[c], m0[c]);                                        \
        }                                                                         \
    }
    if ((e & 1) && e < end) { EDGE1(e); ++e; }       // align to 16B for int4 loads
    for (; e + 4 <= end; e += 4) {
        int4 c01 = *(const int4*)(csr + e);          // (off_s0,off_t0,off_s1,off_t1)
        int4 c23 = *(const int4*)(csr + e + 2);
        float4 h0 = *(const float4*)(hbB + c01.x);
        float4 r0 = *(const float4*)(reB + c01.y);
        float4 h1 = *(const float4*)(hbB + c01.z);
        float4 r1 = *(const float4*)(reB + c01.w);
        float4 h2 = *(const float4*)(hbB + c23.x);
        float4 r2 = *(const float4*)(reB + c23.y);
        float4 h3 = *(const float4*)(hbB + c23.z);
        float4 r3 = *(const float4*)(reB + c23.w);
        float m0[4] = {h0.x * r0.x, h0.y * r0.y, h0.z * r0.z, h0.w * r0.w};
        float m1[4] = {h1.x * r1.x, h1.y * r1.y, h1.z * r1.z, h1.w * r1.w};
        float m2[4] = {h2.x * r2.x, h2.y * r2.y, h2.z * r2.z, h2.w * r2.w};
        float m3[4] = {h3.x * r3.x, h3.y * r3.y, h3.z * r3.z, h3.w * r3.w};
        #pragma unroll
        for (int c = 0; c < 4; ++c) {
            sv[c] += (m0[c] + m1[c]) + (m2[c] + m3[c]);
            ssv[c] = fmaf(m0[c], m0[c], ssv[c]);
            ssv[c] = fmaf(m1[c], m1[c], ssv[c]);
            ssv[c] = fmaf(m2[c], m2[c], ssv[c]);
            ssv[c] = fmaf(m3[c], m3[c], ssv[c]);
            mxv[c] = fmaxf(mxv[c], fmaxf(fmaxf(m0[c], m1[c]), fmaxf(m2[c], m3[c])));
            mnv[c] = fminf(mnv[c], fminf(fminf(m0[c], m1[c]), fminf(m2[c], m3[c])));
        }
    }
    for (; e < end; ++e) EDGE1(e);
#undef EDGE1

    float degf = (float)(end - beg + 1);
    float inv = 1.0f / degf;
    float4 h4 = *(const float4*)(hbB + n * (ND * 4));
    float hself[4] = {h4.x, h4.y, h4.z, h4.w};

    #pragma unroll
    for (int f = 0; f < 5; ++f) {
        float vals[4];
        #pragma unroll
        for (int c = 0; c < 4; ++c) {
            float v;
            if (f == 0) v = hself[c];
            else if (f == 1) v = sv[c] * inv;
            else if (f == 2) v = mxv[c];
            else if (f == 3) v = mnv[c];
            else {
                float mean = sv[c] * inv;
                v = sqrtf(fmaxf(ssv[c] * inv - mean * mean, 0.f));
            }
            vals[c] = v;
        }
        ushort4 vh, vl;
        bf16split(vals[0], vh.x, vl.x);
        bf16split(vals[1], vh.y, vl.y);
        bf16split(vals[2], vh.z, vl.z);
        bf16split(vals[3], vh.w, vl.w);
        *(ushort4*)&ldsAh[rowl][f * 32 + d0] = vh;
        *(ushort4*)&ldsAl[rowl][f * 32 + d0] = vl;
    }
    __syncthreads();

    // -------- phase 2: MFMA update --------
    int mt = w >> 1, nt = w & 1;
    int am = lane & 15, kg = lane >> 4;
    int arow = mt * 16 + am;

    bf16x8v ah[5], al[5];
    #pragma unroll
    for (int c = 0; c < 5; ++c) {
        ah[c] = *(const bf16x8v*)&ldsAh[arow][c * 32 + kg * 8];
        al[c] = *(const bf16x8v*)&ldsAl[arow][c * 32 + kg * 8];
    }
    const bf16x8v* Bh = (const bf16x8v*)(Wph + (size_t)nt * 13 * 64 * 8);
    const bf16x8v* Bl = (const bf16x8v*)(Wpl + (size_t)nt * 13 * 64 * 8);

    f32x4v acc_a = {0.f, 0.f, 0.f, 0.f};
    f32x4v acc2  = {0.f, 0.f, 0.f, 0.f};
    f32x4v acc3  = {0.f, 0.f, 0.f, 0.f};

#define GSTEP(S, C, ACC)                                                          \
    {                                                                             \
        bf16x8v bh = Bh[(S) * 64 + lane];                                         \
        bf16x8v bl = Bl[(S) * 64 + lane];                                         \
        ACC = __builtin_amdgcn_mfma_f32_16x16x32_bf16(ah[C], bh, ACC, 0, 0, 0);   \
        ACC = __builtin_amdgcn_mfma_f32_16x16x32_bf16(ah[C], bl, ACC, 0, 0, 0);   \
        ACC = __builtin_amdgcn_mfma_f32_16x16x32_bf16(al[C], bh, ACC, 0, 0, 0);   \
    }
    GSTEP(0, 0, acc_a)
    GSTEP(1, 1, acc_a) GSTEP(2, 2, acc_a) GSTEP(3, 3, acc_a) GSTEP(4, 4, acc_a)
    GSTEP(5, 1, acc2)  GSTEP(6, 2, acc2)  GSTEP(7, 3, acc2)  GSTEP(8, 4, acc2)
    GSTEP(9, 1, acc3)  GSTEP(10, 2, acc3) GSTEP(11, 3, acc3) GSTEP(12, 4, acc3)
#undef GSTEP

    // Epilogue: C layout col = lane&15, row = 4*(lane>>4)+rr (verified)
    int j = nt * 16 + am;
    float bj = bias[j];
    #pragma unroll
    for (int rr = 0; rr < 4; ++rr) {
        int gi = blk * 32 + mt * 16 + 4 * kg + rr;   // same b
        int node = perm[gi - b * NN];
        float2 sc = scales2[node];
        float v = acc_a[rr] + sc.x * acc2[rr] + sc.y * acc3[rr] + bj;
        size_t o = ((size_t)b * NN + node) * 32 + j;
        hnew[o] = fmaxf(v, 0.f) + hin[o];
    }
}

// ---------------- final MLP scorer: block per (b,t), lane per hidden unit ----------------
__global__ __launch_bounds__(64) void score_kernel(
    const float* __restrict__ hidden, const int* __restrict__ t_index,
    const int* __restrict__ r_index, const float* __restrict__ qw,
    const float* __restrict__ w1, const float* __restrict__ b1,
    const float* __restrict__ w2, const float* __restrict__ b2,
    float* __restrict__ out) {
    int i = blockIdx.x;                       // 0..NB*NT-1
    int b = i / NT;
    int j = threadIdx.x;                      // 0..63
    int node = t_index[i];
    __shared__ float feat[2 * ND];
    if (j < ND) feat[j] = hidden[((size_t)b * NN + node) * ND + j];
    else feat[j] = qw[r_index[b] * ND + (j - ND)];
    __syncthreads();
    float a = b1[j];
    #pragma unroll
    for (int kk = 0; kk < 2 * ND; ++kk) a = fmaf(feat[kk], w1[kk * 2 * ND + j], a);
    float v = fmaxf(a, 0.f) * w2[j];
    #pragma unroll
    for (int off = 32; off > 0; off >>= 1) v += __shfl_down(v, off, 64);
    if (j == 0) out[i] = v + b2[0];
}

extern "C" void kernel_launch(void* const* d_in, const int* in_sizes, int n_in,
                              void* d_out, int out_size, void* d_ws, size_t ws_size,
                              hipStream_t stream) {
    (void)in_sizes; (void)n_in; (void)out_size; (void)ws_size;
    const int* edge_index = (const int*)d_in[0];     // [2][E]
    const int* edge_type  = (const int*)d_in[1];     // [E]
    const int* h_index    = (const int*)d_in[2];     // [B]
    const int* r_index    = (const int*)d_in[3];     // [B]
    const int* t_index    = (const int*)d_in[4];     // [B][T]
    const float* query_weight = (const float*)d_in[5];  // [R][D]
    const float* rel_lin_w    = (const float*)d_in[6];  // [L][D][R*D]
    const float* layer_w      = (const float*)d_in[7];  // [L][13D][D]
    const float* layer_b      = (const float*)d_in[8];  // [L][D]
    const float* mlp_w1 = (const float*)d_in[9];
    const float* mlp_b1 = (const float*)d_in[10];
    const float* mlp_w2 = (const float*)d_in[11];
    const float* mlp_b2 = (const float*)d_in[12];
    float* out = (float*)d_out;

    const int* src = edge_index;
    const int* dst = edge_index + NE;

    char* wsp = (char*)d_ws;
    size_t off = 0;
    auto alloc = [&](size_t bytes) -> void* {
        void* p = wsp + off;
        off += (bytes + 255) & ~(size_t)255;
        return p;
    };
    float* h0      = (float*)alloc(sizeof(float) * M_TOT * ND);
    float* h1      = (float*)alloc(sizeof(float) * M_TOT * ND);
    unsigned short* Wph = (unsigned short*)alloc(sizeof(unsigned short) * NL * 2 * 13 * 64 * 8);
    unsigned short* Wpl = (unsigned short*)alloc(sizeof(unsigned short) * NL * 2 * 13 * 64 * 8);
    float* rel     = (float*)alloc(sizeof(float) * NL * NB * NR * ND);
    int2*  csr     = (int2*)alloc(sizeof(int2) * NE);
    int*   offsets = (int*)alloc(sizeof(int) * (NN + 1));
    int*   ic      = (int*)alloc(sizeof(int) * 2 * NN);   // indeg | cursor (one memset)
    int*   indeg   = ic;
    int*   cursor  = ic + NN;
    int*   perm    = (int*)alloc(sizeof(int) * NN);
    float2* scales2 = (float2*)alloc(sizeof(float2) * NN);

    hipMemsetAsync(ic, 0, sizeof(int) * 2 * NN, stream);
    hipMemsetAsync(h0, 0, sizeof(float) * M_TOT * ND, stream);

    count_kernel<<<(NE + 255) / 256, 256, 0, stream>>>(dst, indeg);
    scan_fused_kernel<<<1, 1024, 0, stream>>>(indeg, offsets, scales2, h0, perm,
                                              h_index, r_index, query_weight);
    scatter_kernel<<<(NE + 255) / 256, 256, 0, stream>>>(src, dst, edge_type, offsets, cursor, csr);
    relwpack_kernel<<<REL_BLOCKS + (NL * 2 * 13 * 64 + 255) / 256, 256, 0, stream>>>(
        query_weight, r_index, rel_lin_w, rel, layer_w, Wph, Wpl);

    float* hin = h0;
    float* hout = h1;
    for (int l = 0; l < NL; ++l) {
        layer_fused_kernel<<<M_TOT / 32, 256, 0, stream>>>(
            hin, hout, rel + (size_t)l * NB * NR * ND,
            Wph + (size_t)l * 2 * 13 * 64 * 8, Wpl + (size_t)l * 2 * 13 * 64 * 8,
            layer_b + (size_t)l * ND, scales2,
            offsets, csr, perm, h_index, r_index, query_weight);
        float* t = hin; hin = hout; hout = t;
    }
    // final hidden is in `hin`

    score_kernel<<<NB * NT, 64, 0, stream>>>(hin, t_index, r_index, query_weight,
                                             mlp_w1, mlp_b1, mlp_w2, mlp_b2, out);
}